// Round 1
// baseline (549.948 us; speedup 1.0000x reference)
//
#include <hip/hip_runtime.h>

#define NN   50000
#define NE   800000
#define INF_ 256
#define HIDF 128
#define OUTF 64

// ---------------- CSR build (counting sort of edges by target) ----------------

__global__ __launch_bounds__(256) void k_zero(int* counts, int* cursor) {
    int i = blockIdx.x * 256 + threadIdx.x;
    if (i < NN) { counts[i] = 0; cursor[i] = 0; }
}

__global__ __launch_bounds__(256) void k_hist(const int* __restrict__ tgt, int* __restrict__ counts) {
    int i = blockIdx.x * 256 + threadIdx.x;
    if (i < NE) atomicAdd(&counts[tgt[i]], 1);
}

// single-block exclusive scan of counts[NN] -> offs[NN+1]
__global__ __launch_bounds__(1024) void k_scan(const int* __restrict__ counts, int* __restrict__ offs) {
    __shared__ int tmp[1024];
    int tid = threadIdx.x;
    int carry = 0;
    for (int base = 0; base < NN; base += 1024) {
        int i = base + tid;
        int v = (i < NN) ? counts[i] : 0;
        tmp[tid] = v;
        __syncthreads();
        #pragma unroll
        for (int off = 1; off < 1024; off <<= 1) {
            int add = (tid >= off) ? tmp[tid - off] : 0;
            __syncthreads();
            tmp[tid] += add;
            __syncthreads();
        }
        if (i < NN) offs[i] = carry + tmp[tid] - v;   // exclusive
        carry += tmp[1023];
        __syncthreads();
    }
    if (tid == 0) offs[NN] = carry;
}

__global__ __launch_bounds__(256) void k_scatter(const int* __restrict__ src, const int* __restrict__ tgt,
                                                 const int* __restrict__ offs, int* __restrict__ cursor,
                                                 int* __restrict__ ssrc) {
    int i = blockIdx.x * 256 + threadIdx.x;
    if (i < NE) {
        int t = tgt[i];
        int pos = offs[t] + atomicAdd(&cursor[t], 1);
        ssrc[pos] = src[i];
    }
}

// ---------------- Linear layers ----------------

// H = elu(X @ W1 + b1); block = 256 threads computes 16 rows x 128 cols
__global__ __launch_bounds__(256) void k_linear1(const float* __restrict__ X, const float* __restrict__ W1,
                                                 const float* __restrict__ b1, float* __restrict__ H) {
    __shared__ float Xs[16][INF_];   // 16 KiB
    int row0 = blockIdx.x * 16;
    const float4* Xv = (const float4*)(X + (size_t)row0 * INF_);
    for (int i = threadIdx.x; i < 16 * (INF_ / 4); i += 256)
        ((float4*)Xs[0])[i] = Xv[i];           // tile is contiguous in X
    __syncthreads();

    int col = threadIdx.x & (HIDF - 1);
    int rg  = threadIdx.x >> 7;                // 0..1 -> 8 rows each
    float acc[8] = {0, 0, 0, 0, 0, 0, 0, 0};
    for (int k = 0; k < INF_; k += 4) {
        float w0 = W1[(k + 0) * HIDF + col];
        float w1 = W1[(k + 1) * HIDF + col];
        float w2 = W1[(k + 2) * HIDF + col];
        float w3 = W1[(k + 3) * HIDF + col];
        #pragma unroll
        for (int r = 0; r < 8; r++) {
            float4 x = *(const float4*)&Xs[rg * 8 + r][k];   // broadcast ds_read_b128
            acc[r] += x.x * w0 + x.y * w1 + x.z * w2 + x.w * w3;
        }
    }
    float bias = b1[col];
    #pragma unroll
    for (int r = 0; r < 8; r++) {
        float v = acc[r] + bias;
        v = v > 0.f ? v : expm1f(v);           // elu
        H[(size_t)(row0 + rg * 8 + r) * HIDF + col] = v;
    }
}

// O = Hagg @ W2 + b2; block = 256 threads computes 16 rows x 64 cols
__global__ __launch_bounds__(256) void k_linear2(const float* __restrict__ Hin, const float* __restrict__ W2,
                                                 const float* __restrict__ b2, float* __restrict__ O) {
    __shared__ float Xs[16][HIDF];   // 8 KiB
    int row0 = blockIdx.x * 16;
    const float4* Xv = (const float4*)(Hin + (size_t)row0 * HIDF);
    for (int i = threadIdx.x; i < 16 * (HIDF / 4); i += 256)
        ((float4*)Xs[0])[i] = Xv[i];
    __syncthreads();

    int col = threadIdx.x & (OUTF - 1);
    int rg  = threadIdx.x >> 6;                // 0..3 -> 4 rows each
    float acc[4] = {0, 0, 0, 0};
    for (int k = 0; k < HIDF; k += 4) {
        float w0 = W2[(k + 0) * OUTF + col];
        float w1 = W2[(k + 1) * OUTF + col];
        float w2 = W2[(k + 2) * OUTF + col];
        float w3 = W2[(k + 3) * OUTF + col];
        #pragma unroll
        for (int r = 0; r < 4; r++) {
            float4 x = *(const float4*)&Xs[rg * 4 + r][k];
            acc[r] += x.x * w0 + x.y * w1 + x.z * w2 + x.w * w3;
        }
    }
    float bias = b2[col];
    #pragma unroll
    for (int r = 0; r < 4; r++)
        O[(size_t)(row0 + rg * 4 + r) * OUTF + col] = acc[r] + bias;
}

// ---------------- per-node attention scalars ----------------

__global__ __launch_bounds__(256) void k_s1(const float* __restrict__ H, const float* __restrict__ a1w,
                                            float* __restrict__ s1s, float* __restrict__ s1t) {
    int wid  = (blockIdx.x * 256 + threadIdx.x) >> 6;
    int lane = threadIdx.x & 63;
    if (wid >= NN) return;
    float2 h  = ((const float2*)(H + (size_t)wid * HIDF))[lane];
    float2 as = ((const float2*)a1w)[lane];
    float2 at = ((const float2*)(a1w + HIDF))[lane];
    float vs = h.x * as.x + h.y * as.y;
    float vt = h.x * at.x + h.y * at.y;
    #pragma unroll
    for (int o = 32; o > 0; o >>= 1) { vs += __shfl_xor(vs, o); vt += __shfl_xor(vt, o); }
    if (lane == 0) { s1s[wid] = vs; s1t[wid] = vt; }
}

__global__ __launch_bounds__(256) void k_s2(const float* __restrict__ O, const float* __restrict__ a2w,
                                            float* __restrict__ s2s, float* __restrict__ s2t) {
    int wid  = (blockIdx.x * 256 + threadIdx.x) >> 6;
    int lane = threadIdx.x & 63;
    if (wid >= NN) return;
    float v  = O[(size_t)wid * OUTF + lane];
    float vs = v * a2w[lane];
    float vt = v * a2w[OUTF + lane];
    #pragma unroll
    for (int o = 32; o > 0; o >>= 1) { vs += __shfl_xor(vs, o); vt += __shfl_xor(vt, o); }
    if (lane == 0) { s2s[wid] = vs; s2t[wid] = vt; }
}

// ---------------- online-softmax aggregation, one wave per target node ----------------

__global__ __launch_bounds__(256) void k_agg1(const float* __restrict__ H, const int* __restrict__ offs,
                                              const int* __restrict__ ssrc, const float* __restrict__ s1s,
                                              const float* __restrict__ s1t, const float* __restrict__ a1b,
                                              float* __restrict__ Hagg) {
    int wid  = (blockIdx.x * 256 + threadIdx.x) >> 6;
    int lane = threadIdx.x & 63;
    if (wid >= NN) return;
    int beg = offs[wid], end = offs[wid + 1];
    float bias = a1b[0];
    float st = s1t[wid];
    float m = -INFINITY, l = 0.f, acc0 = 0.f, acc1 = 0.f;
    for (int i = beg; i < end; i++) {
        int s = ssrc[i];
        float a = s1s[s] + st + bias;
        a = a >= 0.f ? a : 0.2f * a;           // leaky_relu(0.2)
        float mn = fmaxf(m, a);
        float sc = __expf(m - mn);             // exp(-inf)=0 on first iter
        float w  = __expf(a - mn);
        float2 x = ((const float2*)(H + (size_t)s * HIDF))[lane];
        l    = l * sc + w;
        acc0 = acc0 * sc + w * x.x;
        acc1 = acc1 * sc + w * x.y;
        m = mn;
    }
    float inv = 1.f / (l + 1e-16f);
    float2 r; r.x = acc0 * inv; r.y = acc1 * inv;
    ((float2*)(Hagg + (size_t)wid * HIDF))[lane] = r;
}

// layer-2 aggregation fused with log_softmax (d=64 -> one feature per lane)
__global__ __launch_bounds__(256) void k_agg2(const float* __restrict__ O, const int* __restrict__ offs,
                                              const int* __restrict__ ssrc, const float* __restrict__ s2s,
                                              const float* __restrict__ s2t, const float* __restrict__ a2b,
                                              float* __restrict__ out) {
    int wid  = (blockIdx.x * 256 + threadIdx.x) >> 6;
    int lane = threadIdx.x & 63;
    if (wid >= NN) return;
    int beg = offs[wid], end = offs[wid + 1];
    float bias = a2b[0];
    float st = s2t[wid];
    float m = -INFINITY, l = 0.f, acc = 0.f;
    for (int i = beg; i < end; i++) {
        int s = ssrc[i];
        float a = s2s[s] + st + bias;
        a = a >= 0.f ? a : 0.2f * a;
        float mn = fmaxf(m, a);
        float sc = __expf(m - mn);
        float w  = __expf(a - mn);
        float x  = O[(size_t)s * OUTF + lane];
        l   = l * sc + w;
        acc = acc * sc + w * x;
        m = mn;
    }
    float v = acc / (l + 1e-16f);
    // log_softmax across the 64 lanes (= 64 output features)
    float mx = v;
    #pragma unroll
    for (int o = 32; o > 0; o >>= 1) mx = fmaxf(mx, __shfl_xor(mx, o));
    float e = __expf(v - mx);
    float ssum = e;
    #pragma unroll
    for (int o = 32; o > 0; o >>= 1) ssum += __shfl_xor(ssum, o);
    out[(size_t)wid * OUTF + lane] = (v - mx) - __logf(ssum);
}

// ---------------- launcher ----------------

extern "C" void kernel_launch(void* const* d_in, const int* in_sizes, int n_in,
                              void* d_out, int out_size, void* d_ws, size_t ws_size,
                              hipStream_t stream) {
    const float* X   = (const float*)d_in[0];
    const int*   ei  = (const int*)d_in[1];
    const float* W1  = (const float*)d_in[2];
    const float* b1  = (const float*)d_in[3];
    const float* a1w = (const float*)d_in[4];
    const float* a1b = (const float*)d_in[5];
    const float* W2  = (const float*)d_in[6];
    const float* b2  = (const float*)d_in[7];
    const float* a2w = (const float*)d_in[8];
    const float* a2b = (const float*)d_in[9];
    const int* src = ei;           // edge_index[0]
    const int* tgt = ei + NE;      // edge_index[1]

    char* p = (char*)d_ws;
    size_t off = 0;
    auto alloc = [&](size_t bytes) -> char* {
        char* r = p + off;
        off = (off + bytes + 255) & ~(size_t)255;
        return r;
    };
    float* H      = (float*)alloc((size_t)NN * HIDF * 4);
    float* Hagg   = (float*)alloc((size_t)NN * HIDF * 4);
    float* O      = (float*)alloc((size_t)NN * OUTF * 4);
    float* s1s    = (float*)alloc((size_t)NN * 4);
    float* s1t    = (float*)alloc((size_t)NN * 4);
    float* s2s    = (float*)alloc((size_t)NN * 4);
    float* s2t    = (float*)alloc((size_t)NN * 4);
    int*   counts = (int*)alloc((size_t)NN * 4);
    int*   offs   = (int*)alloc((size_t)(NN + 1) * 4);
    int*   cursor = (int*)alloc((size_t)NN * 4);
    int*   ssrc   = (int*)alloc((size_t)NE * 4);

    k_zero   <<<(NN + 255) / 256, 256, 0, stream>>>(counts, cursor);
    k_hist   <<<(NE + 255) / 256, 256, 0, stream>>>(tgt, counts);
    k_scan   <<<1, 1024, 0, stream>>>(counts, offs);
    k_scatter<<<(NE + 255) / 256, 256, 0, stream>>>(src, tgt, offs, cursor, ssrc);

    k_linear1<<<NN / 16, 256, 0, stream>>>(X, W1, b1, H);
    k_s1     <<<NN / 4, 256, 0, stream>>>(H, a1w, s1s, s1t);
    k_agg1   <<<NN / 4, 256, 0, stream>>>(H, offs, ssrc, s1s, s1t, a1b, Hagg);

    k_linear2<<<NN / 16, 256, 0, stream>>>(Hagg, W2, b2, O);
    k_s2     <<<NN / 4, 256, 0, stream>>>(O, a2w, s2s, s2t);
    k_agg2   <<<NN / 4, 256, 0, stream>>>(O, offs, ssrc, s2s, s2t, a2b, (float*)d_out);
}

// Round 2
// 419.391 us; speedup vs baseline: 1.3113x; 1.3113x over previous
//
#include <hip/hip_runtime.h>

#define NN   50000
#define NE   800000
#define INF_ 256
#define HIDF 128
#define OUTF 64
#define NBLK ((NN + 255) / 256)   // 196 scan blocks

typedef __attribute__((ext_vector_type(8))) short short8;
typedef __attribute__((ext_vector_type(4))) float float4v;

__device__ __forceinline__ short f2bf(float f) {
    union { float f; unsigned u; } v; v.f = f;
    unsigned r = v.u + 0x7fffu + ((v.u >> 16) & 1u);   // round-to-nearest-even
    return (short)(r >> 16);
}

// ---------------- CSR build (counting sort of edges by target) ----------------

__global__ __launch_bounds__(256) void k_zero(int* counts, int* cursor) {
    int i = blockIdx.x * 256 + threadIdx.x;
    if (i < NN) { counts[i] = 0; cursor[i] = 0; }
}

__global__ __launch_bounds__(256) void k_hist(const int* __restrict__ tgt, int* __restrict__ counts) {
    int i = blockIdx.x * 256 + threadIdx.x;
    if (i < NE) atomicAdd(&counts[tgt[i]], 1);
}

// hierarchical scan: block-local exclusive scan + per-block sums
__global__ __launch_bounds__(256) void k_scan1(const int* __restrict__ counts, int* __restrict__ offs,
                                               int* __restrict__ bsum) {
    int i = blockIdx.x * 256 + threadIdx.x;
    int lane = threadIdx.x & 63, wv = threadIdx.x >> 6;
    int v = (i < NN) ? counts[i] : 0;
    int x = v;
    #pragma unroll
    for (int o = 1; o < 64; o <<= 1) {
        int y = __shfl_up(x, o);
        if (lane >= o) x += y;
    }
    __shared__ int ws[4];
    if (lane == 63) ws[wv] = x;
    __syncthreads();
    int add = 0;
    #pragma unroll
    for (int w = 0; w < 4; w++) add += (w < wv) ? ws[w] : 0;
    int incl = x + add;
    if (i < NN) offs[i] = incl - v;                 // local exclusive
    if (threadIdx.x == 255) bsum[blockIdx.x] = incl; // block total (OOB lanes contribute 0)
}

__global__ __launch_bounds__(256) void k_scan2(const int* __restrict__ bsum, int* __restrict__ bpre,
                                               int* __restrict__ offs) {
    int i = threadIdx.x;
    int lane = threadIdx.x & 63, wv = threadIdx.x >> 6;
    int v = (i < NBLK) ? bsum[i] : 0;
    int x = v;
    #pragma unroll
    for (int o = 1; o < 64; o <<= 1) {
        int y = __shfl_up(x, o);
        if (lane >= o) x += y;
    }
    __shared__ int ws[4];
    if (lane == 63) ws[wv] = x;
    __syncthreads();
    int add = 0;
    #pragma unroll
    for (int w = 0; w < 4; w++) add += (w < wv) ? ws[w] : 0;
    int incl = x + add;
    if (i < NBLK) bpre[i] = incl - v;
    if (i == 255) offs[NN] = incl;                  // grand total
}

__global__ __launch_bounds__(256) void k_scan3(int* __restrict__ offs, const int* __restrict__ bpre) {
    int i = blockIdx.x * 256 + threadIdx.x;
    if (i < NN) offs[i] += bpre[blockIdx.x];
}

__global__ __launch_bounds__(256) void k_scatter(const int* __restrict__ src, const int* __restrict__ tgt,
                                                 const int* __restrict__ offs, int* __restrict__ cursor,
                                                 int* __restrict__ ssrc) {
    int i = blockIdx.x * 256 + threadIdx.x;
    if (i < NE) {
        int t = tgt[i];
        int pos = offs[t] + atomicAdd(&cursor[t], 1);
        ssrc[pos] = src[i];
    }
}

// ---------------- Linear layers: bf16 MFMA ----------------

// H = elu(X @ W1 + b1).  M=50000, N=128, K=256.
// Block: 256 thr (4 waves), 128 rows/block; W1^T staged bf16 in LDS (no K-loop barriers).
__global__ __launch_bounds__(256) void k_linear1(const float* __restrict__ X, const float* __restrict__ W1,
                                                 const float* __restrict__ b1, float* __restrict__ H) {
    __shared__ short Bs[HIDF][INF_ + 8];     // [n][k], +8 pad -> 67.6 KB
    // stage W1 (fp32 [K][N] row-major) transposed into LDS as bf16
    for (int idx = threadIdx.x; idx < INF_ * HIDF; idx += 256) {
        int k = idx >> 7;          // /HIDF
        int n = idx & (HIDF - 1);
        Bs[n][k] = f2bf(W1[idx]);
    }
    __syncthreads();

    int w = threadIdx.x >> 6;
    int l = threadIdx.x & 63;
    int m_l = l & 15, q = l >> 4;
    int row0 = blockIdx.x * 128 + w * 32;
    int rA0 = row0 + m_l;
    int rA1 = rA0 + 16;
    int rc0 = rA0 < NN ? rA0 : NN - 1;       // clamp OOB reads
    int rc1 = rA1 < NN ? rA1 : NN - 1;
    const float* pa0 = X + (size_t)rc0 * INF_ + q * 8;
    const float* pa1 = X + (size_t)rc1 * INF_ + q * 8;

    float4v acc[2][8] = {};
    #pragma unroll
    for (int kc = 0; kc < INF_ / 32; kc++) {
        int k0 = kc * 32;
        float4 u0 = *(const float4*)(pa0 + k0);
        float4 u1 = *(const float4*)(pa0 + k0 + 4);
        float4 v0 = *(const float4*)(pa1 + k0);
        float4 v1 = *(const float4*)(pa1 + k0 + 4);
        short8 a0, a1;
        a0[0] = f2bf(u0.x); a0[1] = f2bf(u0.y); a0[2] = f2bf(u0.z); a0[3] = f2bf(u0.w);
        a0[4] = f2bf(u1.x); a0[5] = f2bf(u1.y); a0[6] = f2bf(u1.z); a0[7] = f2bf(u1.w);
        a1[0] = f2bf(v0.x); a1[1] = f2bf(v0.y); a1[2] = f2bf(v0.z); a1[3] = f2bf(v0.w);
        a1[4] = f2bf(v1.x); a1[5] = f2bf(v1.y); a1[6] = f2bf(v1.z); a1[7] = f2bf(v1.w);
        const short* bp = &Bs[m_l][k0 + q * 8];
        #pragma unroll
        for (int n = 0; n < 8; n++) {
            short8 b = *(const short8*)(bp + n * 16 * (INF_ + 8));
            acc[0][n] = __builtin_amdgcn_mfma_f32_16x16x32_bf16(a0, b, acc[0][n], 0, 0, 0);
            acc[1][n] = __builtin_amdgcn_mfma_f32_16x16x32_bf16(a1, b, acc[1][n], 0, 0, 0);
        }
    }

    #pragma unroll
    for (int n = 0; n < 8; n++) {
        int col = n * 16 + m_l;
        float bias = b1[col];
        #pragma unroll
        for (int t = 0; t < 2; t++) {
            #pragma unroll
            for (int r = 0; r < 4; r++) {
                int row = row0 + t * 16 + q * 4 + r;
                if (row < NN) {
                    float v = acc[t][n][r] + bias;
                    v = v > 0.f ? v : expm1f(v);   // elu
                    H[(size_t)row * HIDF + col] = v;
                }
            }
        }
    }
}

// O = Hagg @ W2 + b2.  M=50000, N=64, K=128.
__global__ __launch_bounds__(256) void k_linear2(const float* __restrict__ Hin, const float* __restrict__ W2,
                                                 const float* __restrict__ b2, float* __restrict__ O) {
    __shared__ short Bs[OUTF][HIDF + 8];     // 17.4 KB
    for (int idx = threadIdx.x; idx < HIDF * OUTF; idx += 256) {
        int k = idx >> 6;          // /OUTF
        int n = idx & (OUTF - 1);
        Bs[n][k] = f2bf(W2[idx]);
    }
    __syncthreads();

    int w = threadIdx.x >> 6;
    int l = threadIdx.x & 63;
    int m_l = l & 15, q = l >> 4;
    int row0 = blockIdx.x * 128 + w * 32;
    int rA0 = row0 + m_l;
    int rA1 = rA0 + 16;
    int rc0 = rA0 < NN ? rA0 : NN - 1;
    int rc1 = rA1 < NN ? rA1 : NN - 1;
    const float* pa0 = Hin + (size_t)rc0 * HIDF + q * 8;
    const float* pa1 = Hin + (size_t)rc1 * HIDF + q * 8;

    float4v acc[2][4] = {};
    #pragma unroll
    for (int kc = 0; kc < HIDF / 32; kc++) {
        int k0 = kc * 32;
        float4 u0 = *(const float4*)(pa0 + k0);
        float4 u1 = *(const float4*)(pa0 + k0 + 4);
        float4 v0 = *(const float4*)(pa1 + k0);
        float4 v1 = *(const float4*)(pa1 + k0 + 4);
        short8 a0, a1;
        a0[0] = f2bf(u0.x); a0[1] = f2bf(u0.y); a0[2] = f2bf(u0.z); a0[3] = f2bf(u0.w);
        a0[4] = f2bf(u1.x); a0[5] = f2bf(u1.y); a0[6] = f2bf(u1.z); a0[7] = f2bf(u1.w);
        a1[0] = f2bf(v0.x); a1[1] = f2bf(v0.y); a1[2] = f2bf(v0.z); a1[3] = f2bf(v0.w);
        a1[4] = f2bf(v1.x); a1[5] = f2bf(v1.y); a1[6] = f2bf(v1.z); a1[7] = f2bf(v1.w);
        const short* bp = &Bs[m_l][k0 + q * 8];
        #pragma unroll
        for (int n = 0; n < 4; n++) {
            short8 b = *(const short8*)(bp + n * 16 * (HIDF + 8));
            acc[0][n] = __builtin_amdgcn_mfma_f32_16x16x32_bf16(a0, b, acc[0][n], 0, 0, 0);
            acc[1][n] = __builtin_amdgcn_mfma_f32_16x16x32_bf16(a1, b, acc[1][n], 0, 0, 0);
        }
    }

    #pragma unroll
    for (int n = 0; n < 4; n++) {
        int col = n * 16 + m_l;
        float bias = b2[col];
        #pragma unroll
        for (int t = 0; t < 2; t++) {
            #pragma unroll
            for (int r = 0; r < 4; r++) {
                int row = row0 + t * 16 + q * 4 + r;
                if (row < NN)
                    O[(size_t)row * OUTF + col] = acc[t][n][r] + bias;
            }
        }
    }
}

// ---------------- per-node attention scalars ----------------

__global__ __launch_bounds__(256) void k_s1(const float* __restrict__ H, const float* __restrict__ a1w,
                                            float* __restrict__ s1s, float* __restrict__ s1t) {
    int wid  = (blockIdx.x * 256 + threadIdx.x) >> 6;
    int lane = threadIdx.x & 63;
    if (wid >= NN) return;
    float2 h  = ((const float2*)(H + (size_t)wid * HIDF))[lane];
    float2 as = ((const float2*)a1w)[lane];
    float2 at = ((const float2*)(a1w + HIDF))[lane];
    float vs = h.x * as.x + h.y * as.y;
    float vt = h.x * at.x + h.y * at.y;
    #pragma unroll
    for (int o = 32; o > 0; o >>= 1) { vs += __shfl_xor(vs, o); vt += __shfl_xor(vt, o); }
    if (lane == 0) { s1s[wid] = vs; s1t[wid] = vt; }
}

__global__ __launch_bounds__(256) void k_s2(const float* __restrict__ O, const float* __restrict__ a2w,
                                            float* __restrict__ s2s, float* __restrict__ s2t) {
    int wid  = (blockIdx.x * 256 + threadIdx.x) >> 6;
    int lane = threadIdx.x & 63;
    if (wid >= NN) return;
    float v  = O[(size_t)wid * OUTF + lane];
    float vs = v * a2w[lane];
    float vt = v * a2w[OUTF + lane];
    #pragma unroll
    for (int o = 32; o > 0; o >>= 1) { vs += __shfl_xor(vs, o); vt += __shfl_xor(vt, o); }
    if (lane == 0) { s2s[wid] = vs; s2t[wid] = vt; }
}

// ---------------- online-softmax aggregation, one wave per target node ----------------

__global__ __launch_bounds__(256) void k_agg1(const float* __restrict__ H, const int* __restrict__ offs,
                                              const int* __restrict__ ssrc, const float* __restrict__ s1s,
                                              const float* __restrict__ s1t, const float* __restrict__ a1b,
                                              float* __restrict__ Hagg) {
    int wid  = (blockIdx.x * 256 + threadIdx.x) >> 6;
    int lane = threadIdx.x & 63;
    if (wid >= NN) return;
    int beg = offs[wid], end = offs[wid + 1];
    float bias = a1b[0];
    float st = s1t[wid];
    float m = -INFINITY, l = 0.f, acc0 = 0.f, acc1 = 0.f;
    for (int i = beg; i < end; i++) {
        int s = ssrc[i];
        float a = s1s[s] + st + bias;
        a = a >= 0.f ? a : 0.2f * a;           // leaky_relu(0.2)
        float mn = fmaxf(m, a);
        float sc = __expf(m - mn);             // exp(-inf)=0 on first iter
        float w  = __expf(a - mn);
        float2 x = ((const float2*)(H + (size_t)s * HIDF))[lane];
        l    = l * sc + w;
        acc0 = acc0 * sc + w * x.x;
        acc1 = acc1 * sc + w * x.y;
        m = mn;
    }
    float inv = 1.f / (l + 1e-16f);
    float2 r; r.x = acc0 * inv; r.y = acc1 * inv;
    ((float2*)(Hagg + (size_t)wid * HIDF))[lane] = r;
}

// layer-2 aggregation fused with log_softmax (d=64 -> one feature per lane)
__global__ __launch_bounds__(256) void k_agg2(const float* __restrict__ O, const int* __restrict__ offs,
                                              const int* __restrict__ ssrc, const float* __restrict__ s2s,
                                              const float* __restrict__ s2t, const float* __restrict__ a2b,
                                              float* __restrict__ out) {
    int wid  = (blockIdx.x * 256 + threadIdx.x) >> 6;
    int lane = threadIdx.x & 63;
    if (wid >= NN) return;
    int beg = offs[wid], end = offs[wid + 1];
    float bias = a2b[0];
    float st = s2t[wid];
    float m = -INFINITY, l = 0.f, acc = 0.f;
    for (int i = beg; i < end; i++) {
        int s = ssrc[i];
        float a = s2s[s] + st + bias;
        a = a >= 0.f ? a : 0.2f * a;
        float mn = fmaxf(m, a);
        float sc = __expf(m - mn);
        float w  = __expf(a - mn);
        float x  = O[(size_t)s * OUTF + lane];
        l   = l * sc + w;
        acc = acc * sc + w * x;
        m = mn;
    }
    float v = acc / (l + 1e-16f);
    float mx = v;
    #pragma unroll
    for (int o = 32; o > 0; o >>= 1) mx = fmaxf(mx, __shfl_xor(mx, o));
    float e = __expf(v - mx);
    float ssum = e;
    #pragma unroll
    for (int o = 32; o > 0; o >>= 1) ssum += __shfl_xor(ssum, o);
    out[(size_t)wid * OUTF + lane] = (v - mx) - __logf(ssum);
}

// ---------------- launcher ----------------

extern "C" void kernel_launch(void* const* d_in, const int* in_sizes, int n_in,
                              void* d_out, int out_size, void* d_ws, size_t ws_size,
                              hipStream_t stream) {
    const float* X   = (const float*)d_in[0];
    const int*   ei  = (const int*)d_in[1];
    const float* W1  = (const float*)d_in[2];
    const float* b1  = (const float*)d_in[3];
    const float* a1w = (const float*)d_in[4];
    const float* a1b = (const float*)d_in[5];
    const float* W2  = (const float*)d_in[6];
    const float* b2  = (const float*)d_in[7];
    const float* a2w = (const float*)d_in[8];
    const float* a2b = (const float*)d_in[9];
    const int* src = ei;           // edge_index[0]
    const int* tgt = ei + NE;      // edge_index[1]

    char* p = (char*)d_ws;
    size_t off = 0;
    auto alloc = [&](size_t bytes) -> char* {
        char* r = p + off;
        off = (off + bytes + 255) & ~(size_t)255;
        return r;
    };
    float* H      = (float*)alloc((size_t)NN * HIDF * 4);
    float* Hagg   = (float*)alloc((size_t)NN * HIDF * 4);
    float* O      = (float*)alloc((size_t)NN * OUTF * 4);
    float* s1s    = (float*)alloc((size_t)NN * 4);
    float* s1t    = (float*)alloc((size_t)NN * 4);
    float* s2s    = (float*)alloc((size_t)NN * 4);
    float* s2t    = (float*)alloc((size_t)NN * 4);
    int*   counts = (int*)alloc((size_t)NN * 4);
    int*   offs   = (int*)alloc((size_t)(NN + 1) * 4);
    int*   cursor = (int*)alloc((size_t)NN * 4);
    int*   ssrc   = (int*)alloc((size_t)NE * 4);
    int*   bsum   = (int*)alloc((size_t)NBLK * 4);
    int*   bpre   = (int*)alloc((size_t)NBLK * 4);

    k_zero   <<<(NN + 255) / 256, 256, 0, stream>>>(counts, cursor);
    k_hist   <<<(NE + 255) / 256, 256, 0, stream>>>(tgt, counts);
    k_scan1  <<<NBLK, 256, 0, stream>>>(counts, offs, bsum);
    k_scan2  <<<1, 256, 0, stream>>>(bsum, bpre, offs);
    k_scan3  <<<NBLK, 256, 0, stream>>>(offs, bpre);
    k_scatter<<<(NE + 255) / 256, 256, 0, stream>>>(src, tgt, offs, cursor, ssrc);

    k_linear1<<<(NN + 127) / 128, 256, 0, stream>>>(X, W1, b1, H);
    k_s1     <<<NN / 4, 256, 0, stream>>>(H, a1w, s1s, s1t);
    k_agg1   <<<NN / 4, 256, 0, stream>>>(H, offs, ssrc, s1s, s1t, a1b, Hagg);

    k_linear2<<<(NN + 127) / 128, 256, 0, stream>>>(Hagg, W2, b2, O);
    k_s2     <<<NN / 4, 256, 0, stream>>>(O, a2w, s2s, s2t);
    k_agg2   <<<NN / 4, 256, 0, stream>>>(O, offs, ssrc, s2s, s2t, a2b, (float*)d_out);
}

// Round 3
// 367.970 us; speedup vs baseline: 1.4945x; 1.1397x over previous
//
#include <hip/hip_runtime.h>

#define NN   50000
#define NE   800000
#define INF_ 256
#define HIDF 128
#define OUTF 64
#define NBLK ((NN + 255) / 256)   // 196 scan blocks

typedef __attribute__((ext_vector_type(8))) short short8;
typedef __attribute__((ext_vector_type(4))) float float4v;

__device__ __forceinline__ short f2bf(float f) {
    union { float f; unsigned u; } v; v.f = f;
    unsigned r = v.u + 0x7fffu + ((v.u >> 16) & 1u);   // round-to-nearest-even
    return (short)(r >> 16);
}

// ---------------- CSR build (counting sort of edges by target) ----------------

__global__ __launch_bounds__(256) void k_zero(int* counts, int* cursor) {
    int i = blockIdx.x * 256 + threadIdx.x;
    if (i < NN) { counts[i] = 0; cursor[i] = 0; }
}

__global__ __launch_bounds__(256) void k_hist(const int* __restrict__ tgt, int* __restrict__ counts) {
    int i = blockIdx.x * 256 + threadIdx.x;
    if (i < NE) atomicAdd(&counts[tgt[i]], 1);
}

// hierarchical scan: block-local exclusive scan + per-block sums
__global__ __launch_bounds__(256) void k_scan1(const int* __restrict__ counts, int* __restrict__ offs,
                                               int* __restrict__ bsum) {
    int i = blockIdx.x * 256 + threadIdx.x;
    int lane = threadIdx.x & 63, wv = threadIdx.x >> 6;
    int v = (i < NN) ? counts[i] : 0;
    int x = v;
    #pragma unroll
    for (int o = 1; o < 64; o <<= 1) {
        int y = __shfl_up(x, o);
        if (lane >= o) x += y;
    }
    __shared__ int ws[4];
    if (lane == 63) ws[wv] = x;
    __syncthreads();
    int add = 0;
    #pragma unroll
    for (int w = 0; w < 4; w++) add += (w < wv) ? ws[w] : 0;
    int incl = x + add;
    if (i < NN) offs[i] = incl - v;                 // local exclusive
    if (threadIdx.x == 255) bsum[blockIdx.x] = incl; // block total
}

__global__ __launch_bounds__(256) void k_scan2(const int* __restrict__ bsum, int* __restrict__ bpre,
                                               int* __restrict__ offs) {
    int i = threadIdx.x;
    int lane = threadIdx.x & 63, wv = threadIdx.x >> 6;
    int v = (i < NBLK) ? bsum[i] : 0;
    int x = v;
    #pragma unroll
    for (int o = 1; o < 64; o <<= 1) {
        int y = __shfl_up(x, o);
        if (lane >= o) x += y;
    }
    __shared__ int ws[4];
    if (lane == 63) ws[wv] = x;
    __syncthreads();
    int add = 0;
    #pragma unroll
    for (int w = 0; w < 4; w++) add += (w < wv) ? ws[w] : 0;
    int incl = x + add;
    if (i < NBLK) bpre[i] = incl - v;
    if (i == 255) offs[NN] = incl;                  // grand total
}

__global__ __launch_bounds__(256) void k_scan3(int* __restrict__ offs, const int* __restrict__ bpre) {
    int i = blockIdx.x * 256 + threadIdx.x;
    if (i < NN) offs[i] += bpre[blockIdx.x];
}

__global__ __launch_bounds__(256) void k_scatter(const int* __restrict__ src, const int* __restrict__ tgt,
                                                 const int* __restrict__ offs, int* __restrict__ cursor,
                                                 int* __restrict__ ssrc) {
    int i = blockIdx.x * 256 + threadIdx.x;
    if (i < NE) {
        int t = tgt[i];
        int pos = offs[t] + atomicAdd(&cursor[t], 1);
        ssrc[pos] = src[i];
    }
}

// ---------------- Linear layers: bf16 MFMA ----------------

// H = elu(X @ W1 + b1).  M=50000, N=128, K=256.
__global__ __launch_bounds__(256) void k_linear1(const float* __restrict__ X, const float* __restrict__ W1,
                                                 const float* __restrict__ b1, float* __restrict__ H) {
    __shared__ short Bs[HIDF][INF_ + 8];
    for (int idx = threadIdx.x; idx < INF_ * HIDF; idx += 256) {
        int k = idx >> 7;
        int n = idx & (HIDF - 1);
        Bs[n][k] = f2bf(W1[idx]);
    }
    __syncthreads();

    int w = threadIdx.x >> 6;
    int l = threadIdx.x & 63;
    int m_l = l & 15, q = l >> 4;
    int row0 = blockIdx.x * 128 + w * 32;
    int rA0 = row0 + m_l;
    int rA1 = rA0 + 16;
    int rc0 = rA0 < NN ? rA0 : NN - 1;
    int rc1 = rA1 < NN ? rA1 : NN - 1;
    const float* pa0 = X + (size_t)rc0 * INF_ + q * 8;
    const float* pa1 = X + (size_t)rc1 * INF_ + q * 8;

    float4v acc[2][8] = {};
    #pragma unroll
    for (int kc = 0; kc < INF_ / 32; kc++) {
        int k0 = kc * 32;
        float4 u0 = *(const float4*)(pa0 + k0);
        float4 u1 = *(const float4*)(pa0 + k0 + 4);
        float4 v0 = *(const float4*)(pa1 + k0);
        float4 v1 = *(const float4*)(pa1 + k0 + 4);
        short8 a0, a1;
        a0[0] = f2bf(u0.x); a0[1] = f2bf(u0.y); a0[2] = f2bf(u0.z); a0[3] = f2bf(u0.w);
        a0[4] = f2bf(u1.x); a0[5] = f2bf(u1.y); a0[6] = f2bf(u1.z); a0[7] = f2bf(u1.w);
        a1[0] = f2bf(v0.x); a1[1] = f2bf(v0.y); a1[2] = f2bf(v0.z); a1[3] = f2bf(v0.w);
        a1[4] = f2bf(v1.x); a1[5] = f2bf(v1.y); a1[6] = f2bf(v1.z); a1[7] = f2bf(v1.w);
        const short* bp = &Bs[m_l][k0 + q * 8];
        #pragma unroll
        for (int n = 0; n < 8; n++) {
            short8 b = *(const short8*)(bp + n * 16 * (INF_ + 8));
            acc[0][n] = __builtin_amdgcn_mfma_f32_16x16x32_bf16(a0, b, acc[0][n], 0, 0, 0);
            acc[1][n] = __builtin_amdgcn_mfma_f32_16x16x32_bf16(a1, b, acc[1][n], 0, 0, 0);
        }
    }

    #pragma unroll
    for (int n = 0; n < 8; n++) {
        int col = n * 16 + m_l;
        float bias = b1[col];
        #pragma unroll
        for (int t = 0; t < 2; t++) {
            #pragma unroll
            for (int r = 0; r < 4; r++) {
                int row = row0 + t * 16 + q * 4 + r;
                if (row < NN) {
                    float v = acc[t][n][r] + bias;
                    v = v > 0.f ? v : expm1f(v);   // elu
                    H[(size_t)row * HIDF + col] = v;
                }
            }
        }
    }
}

// O = Hagg @ W2 + b2.  M=50000, N=64, K=128.
__global__ __launch_bounds__(256) void k_linear2(const float* __restrict__ Hin, const float* __restrict__ W2,
                                                 const float* __restrict__ b2, float* __restrict__ O) {
    __shared__ short Bs[OUTF][HIDF + 8];
    for (int idx = threadIdx.x; idx < HIDF * OUTF; idx += 256) {
        int k = idx >> 6;
        int n = idx & (OUTF - 1);
        Bs[n][k] = f2bf(W2[idx]);
    }
    __syncthreads();

    int w = threadIdx.x >> 6;
    int l = threadIdx.x & 63;
    int m_l = l & 15, q = l >> 4;
    int row0 = blockIdx.x * 128 + w * 32;
    int rA0 = row0 + m_l;
    int rA1 = rA0 + 16;
    int rc0 = rA0 < NN ? rA0 : NN - 1;
    int rc1 = rA1 < NN ? rA1 : NN - 1;
    const float* pa0 = Hin + (size_t)rc0 * HIDF + q * 8;
    const float* pa1 = Hin + (size_t)rc1 * HIDF + q * 8;

    float4v acc[2][4] = {};
    #pragma unroll
    for (int kc = 0; kc < HIDF / 32; kc++) {
        int k0 = kc * 32;
        float4 u0 = *(const float4*)(pa0 + k0);
        float4 u1 = *(const float4*)(pa0 + k0 + 4);
        float4 v0 = *(const float4*)(pa1 + k0);
        float4 v1 = *(const float4*)(pa1 + k0 + 4);
        short8 a0, a1;
        a0[0] = f2bf(u0.x); a0[1] = f2bf(u0.y); a0[2] = f2bf(u0.z); a0[3] = f2bf(u0.w);
        a0[4] = f2bf(u1.x); a0[5] = f2bf(u1.y); a0[6] = f2bf(u1.z); a0[7] = f2bf(u1.w);
        a1[0] = f2bf(v0.x); a1[1] = f2bf(v0.y); a1[2] = f2bf(v0.z); a1[3] = f2bf(v0.w);
        a1[4] = f2bf(v1.x); a1[5] = f2bf(v1.y); a1[6] = f2bf(v1.z); a1[7] = f2bf(v1.w);
        const short* bp = &Bs[m_l][k0 + q * 8];
        #pragma unroll
        for (int n = 0; n < 4; n++) {
            short8 b = *(const short8*)(bp + n * 16 * (HIDF + 8));
            acc[0][n] = __builtin_amdgcn_mfma_f32_16x16x32_bf16(a0, b, acc[0][n], 0, 0, 0);
            acc[1][n] = __builtin_amdgcn_mfma_f32_16x16x32_bf16(a1, b, acc[1][n], 0, 0, 0);
        }
    }

    #pragma unroll
    for (int n = 0; n < 4; n++) {
        int col = n * 16 + m_l;
        float bias = b2[col];
        #pragma unroll
        for (int t = 0; t < 2; t++) {
            #pragma unroll
            for (int r = 0; r < 4; r++) {
                int row = row0 + t * 16 + q * 4 + r;
                if (row < NN)
                    O[(size_t)row * OUTF + col] = acc[t][n][r] + bias;
            }
        }
    }
}

// ---------------- per-node attention scalars ----------------

__global__ __launch_bounds__(256) void k_s1(const float* __restrict__ H, const float* __restrict__ a1w,
                                            float* __restrict__ s1s, float* __restrict__ s1t) {
    int wid  = (blockIdx.x * 256 + threadIdx.x) >> 6;
    int lane = threadIdx.x & 63;
    if (wid >= NN) return;
    float2 h  = ((const float2*)(H + (size_t)wid * HIDF))[lane];
    float2 as = ((const float2*)a1w)[lane];
    float2 at = ((const float2*)(a1w + HIDF))[lane];
    float vs = h.x * as.x + h.y * as.y;
    float vt = h.x * at.x + h.y * at.y;
    #pragma unroll
    for (int o = 32; o > 0; o >>= 1) { vs += __shfl_xor(vs, o); vt += __shfl_xor(vt, o); }
    if (lane == 0) { s1s[wid] = vs; s1t[wid] = vt; }
}

__global__ __launch_bounds__(256) void k_s2(const float* __restrict__ O, const float* __restrict__ a2w,
                                            float* __restrict__ s2s, float* __restrict__ s2t) {
    int wid  = (blockIdx.x * 256 + threadIdx.x) >> 6;
    int lane = threadIdx.x & 63;
    if (wid >= NN) return;
    float v  = O[(size_t)wid * OUTF + lane];
    float vs = v * a2w[lane];
    float vt = v * a2w[OUTF + lane];
    #pragma unroll
    for (int o = 32; o > 0; o >>= 1) { vs += __shfl_xor(vs, o); vt += __shfl_xor(vt, o); }
    if (lane == 0) { s2s[wid] = vs; s2t[wid] = vt; }
}

// ---------------- per-edge softmax weights (two-pass, wave per node) ----------------

__global__ __launch_bounds__(256) void k_w(const int* __restrict__ offs, const int* __restrict__ ssrc,
                                           const float* __restrict__ ss, const float* __restrict__ st_,
                                           const float* __restrict__ ab, float* __restrict__ w) {
    int wid  = (blockIdx.x * 256 + threadIdx.x) >> 6;
    int lane = threadIdx.x & 63;
    if (wid >= NN) return;
    int beg = __builtin_amdgcn_readfirstlane(offs[wid]);
    int end = __builtin_amdgcn_readfirstlane(offs[wid + 1]);
    float bias = ab[0] + st_[wid];
    // pass 1: max
    float m = -INFINITY;
    for (int i = beg + lane; i < end; i += 64) {
        float a = ss[ssrc[i]] + bias;
        a = a >= 0.f ? a : 0.2f * a;
        m = fmaxf(m, a);
    }
    #pragma unroll
    for (int o = 32; o > 0; o >>= 1) m = fmaxf(m, __shfl_xor(m, o));
    // pass 2: sum
    float sum = 0.f;
    for (int i = beg + lane; i < end; i += 64) {
        float a = ss[ssrc[i]] + bias;
        a = a >= 0.f ? a : 0.2f * a;
        sum += __expf(a - m);
    }
    #pragma unroll
    for (int o = 32; o > 0; o >>= 1) sum += __shfl_xor(sum, o);
    float inv = 1.f / (sum + 1e-16f);
    // pass 3: write normalized weights
    for (int i = beg + lane; i < end; i += 64) {
        float a = ss[ssrc[i]] + bias;
        a = a >= 0.f ? a : 0.2f * a;
        w[i] = __expf(a - m) * inv;
    }
}

// ---------------- aggregation: pure gather-FMA, one wave per target node ----------------

__global__ __launch_bounds__(256) void k_agg1(const float* __restrict__ H, const int* __restrict__ offs,
                                              const int* __restrict__ ssrc, const float* __restrict__ w,
                                              float* __restrict__ Hagg) {
    int wid  = (blockIdx.x * 256 + threadIdx.x) >> 6;
    int lane = threadIdx.x & 63;
    if (wid >= NN) return;
    int beg = __builtin_amdgcn_readfirstlane(offs[wid]);
    int end = __builtin_amdgcn_readfirstlane(offs[wid + 1]);
    const float2* H2 = (const float2*)H;
    float2 acc0 = {0.f, 0.f}, acc1 = {0.f, 0.f};
    int i = beg;
    for (; i + 4 <= end; i += 4) {
        int s0 = ssrc[i], s1 = ssrc[i + 1], s2 = ssrc[i + 2], s3 = ssrc[i + 3];
        float w0 = w[i], w1 = w[i + 1], w2 = w[i + 2], w3 = w[i + 3];
        float2 x0 = H2[(size_t)s0 * 64 + lane];
        float2 x1 = H2[(size_t)s1 * 64 + lane];
        float2 x2 = H2[(size_t)s2 * 64 + lane];
        float2 x3 = H2[(size_t)s3 * 64 + lane];
        acc0.x += w0 * x0.x; acc0.y += w0 * x0.y;
        acc1.x += w1 * x1.x; acc1.y += w1 * x1.y;
        acc0.x += w2 * x2.x; acc0.y += w2 * x2.y;
        acc1.x += w3 * x3.x; acc1.y += w3 * x3.y;
    }
    for (; i < end; i++) {
        int s = ssrc[i];
        float wv = w[i];
        float2 x = H2[(size_t)s * 64 + lane];
        acc0.x += wv * x.x; acc0.y += wv * x.y;
    }
    float2 r; r.x = acc0.x + acc1.x; r.y = acc0.y + acc1.y;
    ((float2*)Hagg)[(size_t)wid * 64 + lane] = r;
}

// layer-2 aggregation fused with log_softmax (d=64 -> one feature per lane)
__global__ __launch_bounds__(256) void k_agg2(const float* __restrict__ O, const int* __restrict__ offs,
                                              const int* __restrict__ ssrc, const float* __restrict__ w,
                                              float* __restrict__ out) {
    int wid  = (blockIdx.x * 256 + threadIdx.x) >> 6;
    int lane = threadIdx.x & 63;
    if (wid >= NN) return;
    int beg = __builtin_amdgcn_readfirstlane(offs[wid]);
    int end = __builtin_amdgcn_readfirstlane(offs[wid + 1]);
    float acc0 = 0.f, acc1 = 0.f;
    int i = beg;
    for (; i + 4 <= end; i += 4) {
        int s0 = ssrc[i], s1 = ssrc[i + 1], s2 = ssrc[i + 2], s3 = ssrc[i + 3];
        float w0 = w[i], w1 = w[i + 1], w2 = w[i + 2], w3 = w[i + 3];
        float x0 = O[(size_t)s0 * OUTF + lane];
        float x1 = O[(size_t)s1 * OUTF + lane];
        float x2 = O[(size_t)s2 * OUTF + lane];
        float x3 = O[(size_t)s3 * OUTF + lane];
        acc0 += w0 * x0; acc1 += w1 * x1;
        acc0 += w2 * x2; acc1 += w3 * x3;
    }
    for (; i < end; i++) {
        acc0 += w[i] * O[(size_t)ssrc[i] * OUTF + lane];
    }
    float v = acc0 + acc1;
    // log_softmax across the 64 lanes (= 64 output features)
    float mx = v;
    #pragma unroll
    for (int o = 32; o > 0; o >>= 1) mx = fmaxf(mx, __shfl_xor(mx, o));
    float e = __expf(v - mx);
    float ssum = e;
    #pragma unroll
    for (int o = 32; o > 0; o >>= 1) ssum += __shfl_xor(ssum, o);
    out[(size_t)wid * OUTF + lane] = (v - mx) - __logf(ssum);
}

// ---------------- launcher ----------------

extern "C" void kernel_launch(void* const* d_in, const int* in_sizes, int n_in,
                              void* d_out, int out_size, void* d_ws, size_t ws_size,
                              hipStream_t stream) {
    const float* X   = (const float*)d_in[0];
    const int*   ei  = (const int*)d_in[1];
    const float* W1  = (const float*)d_in[2];
    const float* b1  = (const float*)d_in[3];
    const float* a1w = (const float*)d_in[4];
    const float* a1b = (const float*)d_in[5];
    const float* W2  = (const float*)d_in[6];
    const float* b2  = (const float*)d_in[7];
    const float* a2w = (const float*)d_in[8];
    const float* a2b = (const float*)d_in[9];
    const int* src = ei;           // edge_index[0]
    const int* tgt = ei + NE;      // edge_index[1]

    char* p = (char*)d_ws;
    size_t off = 0;
    auto alloc = [&](size_t bytes) -> char* {
        char* r = p + off;
        off = (off + bytes + 255) & ~(size_t)255;
        return r;
    };
    float* H      = (float*)alloc((size_t)NN * HIDF * 4);
    float* Hagg   = (float*)alloc((size_t)NN * HIDF * 4);
    float* O      = (float*)alloc((size_t)NN * OUTF * 4);
    float* s1s    = (float*)alloc((size_t)NN * 4);
    float* s1t    = (float*)alloc((size_t)NN * 4);
    float* s2s    = (float*)alloc((size_t)NN * 4);
    float* s2t    = (float*)alloc((size_t)NN * 4);
    int*   counts = (int*)alloc((size_t)NN * 4);
    int*   offs   = (int*)alloc((size_t)(NN + 1) * 4);
    int*   cursor = (int*)alloc((size_t)NN * 4);
    int*   ssrc   = (int*)alloc((size_t)NE * 4);
    int*   bsum   = (int*)alloc((size_t)NBLK * 4);
    int*   bpre   = (int*)alloc((size_t)NBLK * 4);
    float* w1e    = (float*)alloc((size_t)NE * 4);
    float* w2e    = (float*)alloc((size_t)NE * 4);

    k_zero   <<<(NN + 255) / 256, 256, 0, stream>>>(counts, cursor);
    k_hist   <<<(NE + 255) / 256, 256, 0, stream>>>(tgt, counts);
    k_scan1  <<<NBLK, 256, 0, stream>>>(counts, offs, bsum);
    k_scan2  <<<1, 256, 0, stream>>>(bsum, bpre, offs);
    k_scan3  <<<NBLK, 256, 0, stream>>>(offs, bpre);
    k_scatter<<<(NE + 255) / 256, 256, 0, stream>>>(src, tgt, offs, cursor, ssrc);

    k_linear1<<<(NN + 127) / 128, 256, 0, stream>>>(X, W1, b1, H);
    k_s1     <<<NN / 4, 256, 0, stream>>>(H, a1w, s1s, s1t);
    k_w      <<<NN / 4, 256, 0, stream>>>(offs, ssrc, s1s, s1t, a1b, w1e);
    k_agg1   <<<NN / 4, 256, 0, stream>>>(H, offs, ssrc, w1e, Hagg);

    k_linear2<<<(NN + 127) / 128, 256, 0, stream>>>(Hagg, W2, b2, O);
    k_s2     <<<NN / 4, 256, 0, stream>>>(O, a2w, s2s, s2t);
    k_w      <<<NN / 4, 256, 0, stream>>>(offs, ssrc, s2s, s2t, a2b, w2e);
    k_agg2   <<<NN / 4, 256, 0, stream>>>(O, offs, ssrc, w2e, (float*)d_out);
}

// Round 4
// 302.553 us; speedup vs baseline: 1.8177x; 1.2162x over previous
//
#include <hip/hip_runtime.h>

#define NN   50000
#define NE   800000
#define INF_ 256
#define HIDF 128
#define OUTF 64
#define NBLK ((NN + 255) / 256)   // 196 scan blocks

typedef unsigned int uint;
typedef unsigned short ushort;
typedef __attribute__((ext_vector_type(8))) short short8;
typedef __attribute__((ext_vector_type(4))) float float4v;

__device__ __forceinline__ short f2bf(float f) {
    union { float f; unsigned u; } v; v.f = f;
    unsigned r = v.u + 0x7fffu + ((v.u >> 16) & 1u);   // round-to-nearest-even
    return (short)(r >> 16);
}
__device__ __forceinline__ float bflo(uint u) {
    union { uint u; float f; } v; v.u = u << 16; return v.f;
}
__device__ __forceinline__ float bfhi(uint u) {
    union { uint u; float f; } v; v.u = u & 0xffff0000u; return v.f;
}

// ---------------- CSR build (counting sort of edges by target) ----------------

__global__ __launch_bounds__(256) void k_hist(const int* __restrict__ tgt, int* __restrict__ counts) {
    int i = blockIdx.x * 256 + threadIdx.x;
    if (i < NE) atomicAdd(&counts[tgt[i]], 1);
}

__global__ __launch_bounds__(256) void k_scan1(const int* __restrict__ counts, int* __restrict__ offs,
                                               int* __restrict__ bsum) {
    int i = blockIdx.x * 256 + threadIdx.x;
    int lane = threadIdx.x & 63, wv = threadIdx.x >> 6;
    int v = (i < NN) ? counts[i] : 0;
    int x = v;
    #pragma unroll
    for (int o = 1; o < 64; o <<= 1) {
        int y = __shfl_up(x, o);
        if (lane >= o) x += y;
    }
    __shared__ int ws[4];
    if (lane == 63) ws[wv] = x;
    __syncthreads();
    int add = 0;
    #pragma unroll
    for (int w = 0; w < 4; w++) add += (w < wv) ? ws[w] : 0;
    int incl = x + add;
    if (i < NN) offs[i] = incl - v;
    if (threadIdx.x == 255) bsum[blockIdx.x] = incl;
}

__global__ __launch_bounds__(256) void k_scan2(const int* __restrict__ bsum, int* __restrict__ bpre,
                                               int* __restrict__ offs) {
    int i = threadIdx.x;
    int lane = threadIdx.x & 63, wv = threadIdx.x >> 6;
    int v = (i < NBLK) ? bsum[i] : 0;
    int x = v;
    #pragma unroll
    for (int o = 1; o < 64; o <<= 1) {
        int y = __shfl_up(x, o);
        if (lane >= o) x += y;
    }
    __shared__ int ws[4];
    if (lane == 63) ws[wv] = x;
    __syncthreads();
    int add = 0;
    #pragma unroll
    for (int w = 0; w < 4; w++) add += (w < wv) ? ws[w] : 0;
    int incl = x + add;
    if (i < NBLK) bpre[i] = incl - v;
    if (i == 255) offs[NN] = incl;
}

__global__ __launch_bounds__(256) void k_scan3(int* __restrict__ offs, const int* __restrict__ bpre) {
    int i = blockIdx.x * 256 + threadIdx.x;
    if (i < NN) offs[i] += bpre[blockIdx.x];
}

__global__ __launch_bounds__(256) void k_scatter(const int* __restrict__ src, const int* __restrict__ tgt,
                                                 const int* __restrict__ offs, int* __restrict__ cursor,
                                                 int* __restrict__ ssrc) {
    int i = blockIdx.x * 256 + threadIdx.x;
    if (i < NE) {
        int t = tgt[i];
        int pos = offs[t] + atomicAdd(&cursor[t], 1);
        ssrc[pos] = src[i];
    }
}

// ---------------- Linear layers: bf16 MFMA ----------------

// Hbf = bf16(elu(X @ W1 + b1)).  M=50000, N=128, K=256.
__global__ __launch_bounds__(256) void k_linear1(const float* __restrict__ X, const float* __restrict__ W1,
                                                 const float* __restrict__ b1, ushort* __restrict__ Hb) {
    __shared__ short Bs[HIDF][INF_ + 8];
    for (int idx = threadIdx.x; idx < INF_ * HIDF; idx += 256) {
        int k = idx >> 7;
        int n = idx & (HIDF - 1);
        Bs[n][k] = f2bf(W1[idx]);
    }
    __syncthreads();

    int w = threadIdx.x >> 6;
    int l = threadIdx.x & 63;
    int m_l = l & 15, q = l >> 4;
    int row0 = blockIdx.x * 128 + w * 32;
    int rA0 = row0 + m_l;
    int rA1 = rA0 + 16;
    int rc0 = rA0 < NN ? rA0 : NN - 1;
    int rc1 = rA1 < NN ? rA1 : NN - 1;
    const float* pa0 = X + (size_t)rc0 * INF_ + q * 8;
    const float* pa1 = X + (size_t)rc1 * INF_ + q * 8;

    float4v acc[2][8] = {};
    #pragma unroll
    for (int kc = 0; kc < INF_ / 32; kc++) {
        int k0 = kc * 32;
        float4 u0 = *(const float4*)(pa0 + k0);
        float4 u1 = *(const float4*)(pa0 + k0 + 4);
        float4 v0 = *(const float4*)(pa1 + k0);
        float4 v1 = *(const float4*)(pa1 + k0 + 4);
        short8 a0, a1;
        a0[0] = f2bf(u0.x); a0[1] = f2bf(u0.y); a0[2] = f2bf(u0.z); a0[3] = f2bf(u0.w);
        a0[4] = f2bf(u1.x); a0[5] = f2bf(u1.y); a0[6] = f2bf(u1.z); a0[7] = f2bf(u1.w);
        a1[0] = f2bf(v0.x); a1[1] = f2bf(v0.y); a1[2] = f2bf(v0.z); a1[3] = f2bf(v0.w);
        a1[4] = f2bf(v1.x); a1[5] = f2bf(v1.y); a1[6] = f2bf(v1.z); a1[7] = f2bf(v1.w);
        const short* bp = &Bs[m_l][k0 + q * 8];
        #pragma unroll
        for (int n = 0; n < 8; n++) {
            short8 b = *(const short8*)(bp + n * 16 * (INF_ + 8));
            acc[0][n] = __builtin_amdgcn_mfma_f32_16x16x32_bf16(a0, b, acc[0][n], 0, 0, 0);
            acc[1][n] = __builtin_amdgcn_mfma_f32_16x16x32_bf16(a1, b, acc[1][n], 0, 0, 0);
        }
    }

    #pragma unroll
    for (int n = 0; n < 8; n++) {
        int col = n * 16 + m_l;
        float bias = b1[col];
        #pragma unroll
        for (int t = 0; t < 2; t++) {
            #pragma unroll
            for (int r = 0; r < 4; r++) {
                int row = row0 + t * 16 + q * 4 + r;
                if (row < NN) {
                    float v = acc[t][n][r] + bias;
                    v = v > 0.f ? v : expm1f(v);   // elu
                    Hb[(size_t)row * HIDF + col] = (ushort)f2bf(v);
                }
            }
        }
    }
}

// Obf = bf16(Haggbf @ W2 + b2).  M=50000, N=64, K=128, A already bf16.
__global__ __launch_bounds__(256) void k_linear2(const short* __restrict__ Hin, const float* __restrict__ W2,
                                                 const float* __restrict__ b2, ushort* __restrict__ Ob) {
    __shared__ short Bs[OUTF][HIDF + 8];
    for (int idx = threadIdx.x; idx < HIDF * OUTF; idx += 256) {
        int k = idx >> 6;
        int n = idx & (OUTF - 1);
        Bs[n][k] = f2bf(W2[idx]);
    }
    __syncthreads();

    int w = threadIdx.x >> 6;
    int l = threadIdx.x & 63;
    int m_l = l & 15, q = l >> 4;
    int row0 = blockIdx.x * 128 + w * 32;
    int rA0 = row0 + m_l;
    int rA1 = rA0 + 16;
    int rc0 = rA0 < NN ? rA0 : NN - 1;
    int rc1 = rA1 < NN ? rA1 : NN - 1;
    const short* pa0 = Hin + (size_t)rc0 * HIDF + q * 8;
    const short* pa1 = Hin + (size_t)rc1 * HIDF + q * 8;

    float4v acc[2][4] = {};
    #pragma unroll
    for (int kc = 0; kc < HIDF / 32; kc++) {
        int k0 = kc * 32;
        short8 a0 = *(const short8*)(pa0 + k0);
        short8 a1 = *(const short8*)(pa1 + k0);
        const short* bp = &Bs[m_l][k0 + q * 8];
        #pragma unroll
        for (int n = 0; n < 4; n++) {
            short8 b = *(const short8*)(bp + n * 16 * (HIDF + 8));
            acc[0][n] = __builtin_amdgcn_mfma_f32_16x16x32_bf16(a0, b, acc[0][n], 0, 0, 0);
            acc[1][n] = __builtin_amdgcn_mfma_f32_16x16x32_bf16(a1, b, acc[1][n], 0, 0, 0);
        }
    }

    #pragma unroll
    for (int n = 0; n < 4; n++) {
        int col = n * 16 + m_l;
        float bias = b2[col];
        #pragma unroll
        for (int t = 0; t < 2; t++) {
            #pragma unroll
            for (int r = 0; r < 4; r++) {
                int row = row0 + t * 16 + q * 4 + r;
                if (row < NN)
                    Ob[(size_t)row * OUTF + col] = (ushort)f2bf(acc[t][n][r] + bias);
            }
        }
    }
}

// ---------------- per-node attention scalars (bf16 inputs) ----------------

__global__ __launch_bounds__(256) void k_s1(const uint* __restrict__ Hb4, const float* __restrict__ a1w,
                                            float* __restrict__ s1s, float* __restrict__ s1t) {
    int wid  = (blockIdx.x * 256 + threadIdx.x) >> 6;
    int lane = threadIdx.x & 63;
    if (wid >= NN) return;
    uint h = Hb4[(size_t)wid * 64 + lane];          // feats 2*lane, 2*lane+1
    float h0 = bflo(h), h1 = bfhi(h);
    float2 as = ((const float2*)a1w)[lane];
    float2 at = ((const float2*)(a1w + HIDF))[lane];
    float vs = h0 * as.x + h1 * as.y;
    float vt = h0 * at.x + h1 * at.y;
    #pragma unroll
    for (int o = 32; o > 0; o >>= 1) { vs += __shfl_xor(vs, o); vt += __shfl_xor(vt, o); }
    if (lane == 0) { s1s[wid] = vs; s1t[wid] = vt; }
}

// half-wave per node (O row = 32 uints)
__global__ __launch_bounds__(256) void k_s2(const uint* __restrict__ Ob4, const float* __restrict__ a2w,
                                            float* __restrict__ s2s, float* __restrict__ s2t) {
    int wid = (blockIdx.x * 256 + threadIdx.x) >> 5;
    int li  = threadIdx.x & 31;
    if (wid >= NN) return;
    uint o = Ob4[(size_t)wid * 32 + li];
    float v0 = bflo(o), v1 = bfhi(o);
    float2 as = ((const float2*)a2w)[li];
    float2 at = ((const float2*)(a2w + OUTF))[li];
    float vs = v0 * as.x + v1 * as.y;
    float vt = v0 * at.x + v1 * at.y;
    #pragma unroll
    for (int o2 = 16; o2 > 0; o2 >>= 1) { vs += __shfl_xor(vs, o2); vt += __shfl_xor(vt, o2); }
    if (li == 0) { s2s[wid] = vs; s2t[wid] = vt; }
}

// ---------------- fused softmax + gather aggregation, one wave per node ----------------

// layer 1: gathers bf16 H rows (64 uints), writes bf16 Hagg
__global__ __launch_bounds__(256) void k_agg1f(const uint* __restrict__ Hb4, const int* __restrict__ offs,
                                               const int* __restrict__ ssrc, const float* __restrict__ ss,
                                               const float* __restrict__ st_, const float* __restrict__ ab,
                                               uint* __restrict__ Hagg4) {
    int wid  = (blockIdx.x * 256 + threadIdx.x) >> 6;
    int lane = threadIdx.x & 63;
    if (wid >= NN) return;
    int beg = __builtin_amdgcn_readfirstlane(offs[wid]);
    int end = __builtin_amdgcn_readfirstlane(offs[wid + 1]);
    int deg = end - beg;
    float bias = ab[0] + st_[wid];
    float ax = 0.f, ay = 0.f, bx = 0.f, by = 0.f;

    if (deg > 0 && deg <= 64) {
        // ---- fast path: one edge per lane ----
        int my_s = 0; float a = -INFINITY;
        if (lane < deg) {
            my_s = ssrc[beg + lane];
            float t = ss[my_s] + bias;
            a = t >= 0.f ? t : 0.2f * t;
        }
        float m = a;
        #pragma unroll
        for (int o = 32; o > 0; o >>= 1) m = fmaxf(m, __shfl_xor(m, o));
        float e = (lane < deg) ? __expf(a - m) : 0.f;
        float sum = e;
        #pragma unroll
        for (int o = 32; o > 0; o >>= 1) sum += __shfl_xor(sum, o);
        float p = e * (1.f / (sum + 1e-16f));
        for (int j = 0; j < deg; j += 4) {
            int s0 = __shfl(my_s, j),     s1 = __shfl(my_s, j + 1);
            int s2 = __shfl(my_s, j + 2), s3 = __shfl(my_s, j + 3);
            float w0 = __shfl(p, j),     w1 = __shfl(p, j + 1);
            float w2 = __shfl(p, j + 2), w3 = __shfl(p, j + 3);
            uint x0 = Hb4[(size_t)s0 * 64 + lane];
            uint x1 = Hb4[(size_t)s1 * 64 + lane];
            uint x2 = Hb4[(size_t)s2 * 64 + lane];
            uint x3 = Hb4[(size_t)s3 * 64 + lane];
            ax += w0 * bflo(x0); ay += w0 * bfhi(x0);
            bx += w1 * bflo(x1); by += w1 * bfhi(x1);
            ax += w2 * bflo(x2); ay += w2 * bfhi(x2);
            bx += w3 * bflo(x3); by += w3 * bfhi(x3);
        }
    } else if (deg > 64) {
        // ---- rare slow path: strided two-pass then chunked broadcast ----
        float m = -INFINITY;
        for (int i = beg + lane; i < end; i += 64) {
            float t = ss[ssrc[i]] + bias;
            t = t >= 0.f ? t : 0.2f * t;
            m = fmaxf(m, t);
        }
        #pragma unroll
        for (int o = 32; o > 0; o >>= 1) m = fmaxf(m, __shfl_xor(m, o));
        float sum = 0.f;
        for (int i = beg + lane; i < end; i += 64) {
            float t = ss[ssrc[i]] + bias;
            t = t >= 0.f ? t : 0.2f * t;
            sum += __expf(t - m);
        }
        #pragma unroll
        for (int o = 32; o > 0; o >>= 1) sum += __shfl_xor(sum, o);
        float inv = 1.f / (sum + 1e-16f);
        for (int c = beg; c < end; c += 64) {
            int cnt = min(64, end - c);
            int my_s = 0; float p = 0.f;
            if (lane < cnt) {
                my_s = ssrc[c + lane];
                float t = ss[my_s] + bias;
                t = t >= 0.f ? t : 0.2f * t;
                p = __expf(t - m) * inv;
            }
            for (int j = 0; j < cnt; j += 4) {
                int s0 = __shfl(my_s, j),     s1 = __shfl(my_s, j + 1);
                int s2 = __shfl(my_s, j + 2), s3 = __shfl(my_s, j + 3);
                float w0 = __shfl(p, j),     w1 = __shfl(p, j + 1);
                float w2 = __shfl(p, j + 2), w3 = __shfl(p, j + 3);
                uint x0 = Hb4[(size_t)s0 * 64 + lane];
                uint x1 = Hb4[(size_t)s1 * 64 + lane];
                uint x2 = Hb4[(size_t)s2 * 64 + lane];
                uint x3 = Hb4[(size_t)s3 * 64 + lane];
                ax += w0 * bflo(x0); ay += w0 * bfhi(x0);
                bx += w1 * bflo(x1); by += w1 * bfhi(x1);
                ax += w2 * bflo(x2); ay += w2 * bfhi(x2);
                bx += w3 * bflo(x3); by += w3 * bfhi(x3);
            }
        }
    }
    float fx = ax + bx, fy = ay + by;
    uint outv = (uint)(ushort)f2bf(fx) | ((uint)(ushort)f2bf(fy) << 16);
    Hagg4[(size_t)wid * 64 + lane] = outv;
}

// layer 2: gathers bf16 O rows (32 uints; half-wave per edge), fused log_softmax
__global__ __launch_bounds__(256) void k_agg2f(const uint* __restrict__ Ob4, const int* __restrict__ offs,
                                               const int* __restrict__ ssrc, const float* __restrict__ ss,
                                               const float* __restrict__ st_, const float* __restrict__ ab,
                                               float* __restrict__ out) {
    int wid  = (blockIdx.x * 256 + threadIdx.x) >> 6;
    int lane = threadIdx.x & 63;
    if (wid >= NN) return;
    int half = lane >> 5, li = lane & 31;
    int beg = __builtin_amdgcn_readfirstlane(offs[wid]);
    int end = __builtin_amdgcn_readfirstlane(offs[wid + 1]);
    int deg = end - beg;
    float bias = ab[0] + st_[wid];
    float a0 = 0.f, a1 = 0.f;

    if (deg > 0 && deg <= 64) {
        int my_s = 0; float a = -INFINITY;
        if (lane < deg) {
            my_s = ssrc[beg + lane];
            float t = ss[my_s] + bias;
            a = t >= 0.f ? t : 0.2f * t;
        }
        float m = a;
        #pragma unroll
        for (int o = 32; o > 0; o >>= 1) m = fmaxf(m, __shfl_xor(m, o));
        float e = (lane < deg) ? __expf(a - m) : 0.f;
        float sum = e;
        #pragma unroll
        for (int o = 32; o > 0; o >>= 1) sum += __shfl_xor(sum, o);
        float p = e * (1.f / (sum + 1e-16f));
        for (int j = 0; j < deg; j += 4) {
            int e0 = j + half, e1 = j + 2 + half;
            int s0 = __shfl(my_s, e0), s1 = __shfl(my_s, e1);
            float w0 = __shfl(p, e0), w1 = __shfl(p, e1);
            uint x0 = Ob4[(size_t)s0 * 32 + li];
            uint x1 = Ob4[(size_t)s1 * 32 + li];
            a0 += w0 * bflo(x0); a1 += w0 * bfhi(x0);
            a0 += w1 * bflo(x1); a1 += w1 * bfhi(x1);
        }
    } else if (deg > 64) {
        float m = -INFINITY;
        for (int i = beg + lane; i < end; i += 64) {
            float t = ss[ssrc[i]] + bias;
            t = t >= 0.f ? t : 0.2f * t;
            m = fmaxf(m, t);
        }
        #pragma unroll
        for (int o = 32; o > 0; o >>= 1) m = fmaxf(m, __shfl_xor(m, o));
        float sum = 0.f;
        for (int i = beg + lane; i < end; i += 64) {
            float t = ss[ssrc[i]] + bias;
            t = t >= 0.f ? t : 0.2f * t;
            sum += __expf(t - m);
        }
        #pragma unroll
        for (int o = 32; o > 0; o >>= 1) sum += __shfl_xor(sum, o);
        float inv = 1.f / (sum + 1e-16f);
        for (int c = beg; c < end; c += 64) {
            int cnt = min(64, end - c);
            int my_s = 0; float p = 0.f;
            if (lane < cnt) {
                my_s = ssrc[c + lane];
                float t = ss[my_s] + bias;
                t = t >= 0.f ? t : 0.2f * t;
                p = __expf(t - m) * inv;
            }
            for (int j = 0; j < cnt; j += 4) {
                int e0 = j + half, e1 = j + 2 + half;
                int s0 = __shfl(my_s, e0), s1 = __shfl(my_s, e1);
                float w0 = __shfl(p, e0), w1 = __shfl(p, e1);
                uint x0 = Ob4[(size_t)s0 * 32 + li];
                uint x1 = Ob4[(size_t)s1 * 32 + li];
                a0 += w0 * bflo(x0); a1 += w0 * bfhi(x0);
                a0 += w1 * bflo(x1); a1 += w1 * bfhi(x1);
            }
        }
    }
    // combine the two edge-halves (each lane's feats live in both halves)
    a0 += __shfl_xor(a0, 32);
    a1 += __shfl_xor(a1, 32);
    // log_softmax over 64 feats (2 per lane across each 32-lane half)
    float mx = fmaxf(a0, a1);
    #pragma unroll
    for (int o = 16; o > 0; o >>= 1) mx = fmaxf(mx, __shfl_xor(mx, o));
    float es = __expf(a0 - mx) + __expf(a1 - mx);
    #pragma unroll
    for (int o = 16; o > 0; o >>= 1) es += __shfl_xor(es, o);
    float lg = __logf(es);
    if (half == 0) {
        float2 r; r.x = a0 - mx - lg; r.y = a1 - mx - lg;
        ((float2*)out)[(size_t)wid * 32 + li] = r;
    }
}

// ---------------- launcher ----------------

extern "C" void kernel_launch(void* const* d_in, const int* in_sizes, int n_in,
                              void* d_out, int out_size, void* d_ws, size_t ws_size,
                              hipStream_t stream) {
    const float* X   = (const float*)d_in[0];
    const int*   ei  = (const int*)d_in[1];
    const float* W1  = (const float*)d_in[2];
    const float* b1  = (const float*)d_in[3];
    const float* a1w = (const float*)d_in[4];
    const float* a1b = (const float*)d_in[5];
    const float* W2  = (const float*)d_in[6];
    const float* b2  = (const float*)d_in[7];
    const float* a2w = (const float*)d_in[8];
    const float* a2b = (const float*)d_in[9];
    const int* src = ei;           // edge_index[0]
    const int* tgt = ei + NE;      // edge_index[1]

    char* p = (char*)d_ws;
    size_t off = 0;
    auto alloc = [&](size_t bytes) -> char* {
        char* r = p + off;
        off = (off + bytes + 255) & ~(size_t)255;
        return r;
    };
    ushort* Hb    = (ushort*)alloc((size_t)NN * HIDF * 2);
    ushort* Hagg  = (ushort*)alloc((size_t)NN * HIDF * 2);
    ushort* Ob    = (ushort*)alloc((size_t)NN * OUTF * 2);
    float* s1s    = (float*)alloc((size_t)NN * 4);
    float* s1t    = (float*)alloc((size_t)NN * 4);
    float* s2s    = (float*)alloc((size_t)NN * 4);
    float* s2t    = (float*)alloc((size_t)NN * 4);
    int*   czero  = (int*)alloc((size_t)2 * NN * 4);   // counts | cursor
    int*   counts = czero;
    int*   cursor = czero + NN;
    int*   offs   = (int*)alloc((size_t)(NN + 1) * 4);
    int*   ssrc   = (int*)alloc((size_t)NE * 4);
    int*   bsum   = (int*)alloc((size_t)NBLK * 4);
    int*   bpre   = (int*)alloc((size_t)NBLK * 4);

    hipMemsetAsync(czero, 0, (size_t)2 * NN * 4, stream);
    k_hist   <<<(NE + 255) / 256, 256, 0, stream>>>(tgt, counts);
    k_scan1  <<<NBLK, 256, 0, stream>>>(counts, offs, bsum);
    k_scan2  <<<1, 256, 0, stream>>>(bsum, bpre, offs);
    k_scan3  <<<NBLK, 256, 0, stream>>>(offs, bpre);
    k_scatter<<<(NE + 255) / 256, 256, 0, stream>>>(src, tgt, offs, cursor, ssrc);

    k_linear1<<<(NN + 127) / 128, 256, 0, stream>>>(X, W1, b1, Hb);
    k_s1     <<<NN / 4, 256, 0, stream>>>((const uint*)Hb, a1w, s1s, s1t);
    k_agg1f  <<<NN / 4, 256, 0, stream>>>((const uint*)Hb, offs, ssrc, s1s, s1t, a1b, (uint*)Hagg);

    k_linear2<<<(NN + 127) / 128, 256, 0, stream>>>((const short*)Hagg, W2, b2, Ob);
    k_s2     <<<NN / 8, 256, 0, stream>>>((const uint*)Ob, a2w, s2s, s2t);
    k_agg2f  <<<NN / 4, 256, 0, stream>>>((const uint*)Ob, offs, ssrc, s2s, s2t, a2b, (float*)d_out);
}

// Round 5
// 239.777 us; speedup vs baseline: 2.2936x; 1.2618x over previous
//
#include <hip/hip_runtime.h>

#define NN    50000
#define NE    800000
#define INF_  256
#define HIDF  128
#define OUTF  64
#define NBUCK 196        // ceil(50000/256) coarse buckets, 256 nodes each
#define CAP   5120       // per-bucket region capacity (mean 4082, std 64 -> 16 sigma)
#define CHUNK 2048       // edges per pass-1 block

typedef unsigned int uint;
typedef unsigned short ushort;
typedef __attribute__((ext_vector_type(8))) short short8;
typedef __attribute__((ext_vector_type(4))) float float4v;

__device__ __forceinline__ short f2bf(float f) {
    union { float f; unsigned u; } v; v.f = f;
    unsigned r = v.u + 0x7fffu + ((v.u >> 16) & 1u);   // round-to-nearest-even
    return (short)(r >> 16);
}
__device__ __forceinline__ float bflo(uint u) {
    union { uint u; float f; } v; v.u = u << 16; return v.f;
}
__device__ __forceinline__ float bfhi(uint u) {
    union { uint u; float f; } v; v.u = u & 0xffff0000u; return v.f;
}

// 256-thread block exclusive scan (ws = 4-int shared scratch). All 256 call.
__device__ __forceinline__ int excl_scan256(int v, int* ws) {
    int lane = threadIdx.x & 63, wv = threadIdx.x >> 6;
    int x = v;
    #pragma unroll
    for (int o = 1; o < 64; o <<= 1) {
        int y = __shfl_up(x, o);
        if (lane >= o) x += y;
    }
    if (lane == 63) ws[wv] = x;
    __syncthreads();
    int add = 0;
    #pragma unroll
    for (int w = 0; w < 4; w++) add += (w < wv) ? ws[w] : 0;
    return x + add - v;
}

// ---------------- two-pass bucket sort of edges by target ----------------

// pass 1: bin edges into 196 coarse buckets (256 nodes each), LDS-staged
__global__ __launch_bounds__(256) void k_part1(const int* __restrict__ src, const int* __restrict__ tgt,
                                               int* __restrict__ bcur, uint2* __restrict__ pairs) {
    __shared__ int hist[NBUCK], lofs[NBUCK], cur[NBUCK], gstart[NBUCK];
    __shared__ int ws[4];
    __shared__ int ltgt[CHUNK], lsrc[CHUNK];
    int tid = threadIdx.x;
    for (int i = tid; i < NBUCK; i += 256) hist[i] = 0;
    __syncthreads();

    int base = blockIdx.x * CHUNK;
    int cnt = NE - base; if (cnt > CHUNK) cnt = CHUNK;

    int t_[8], s_[8];
    #pragma unroll
    for (int k = 0; k < 8; k++) {
        int idx = k * 256 + tid;
        if (idx < cnt) {
            int j = base + idx;
            t_[k] = tgt[j]; s_[k] = src[j];
            atomicAdd(&hist[t_[k] >> 8], 1);
        } else t_[k] = -1;
    }
    __syncthreads();

    int v = (tid < NBUCK) ? hist[tid] : 0;
    int excl = excl_scan256(v, ws);
    if (tid < NBUCK) {
        lofs[tid] = excl;
        cur[tid] = excl;
        gstart[tid] = atomicAdd(&bcur[tid], v);   // reserve global bucket space
    }
    __syncthreads();

    #pragma unroll
    for (int k = 0; k < 8; k++) {
        if (t_[k] >= 0) {
            int b = t_[k] >> 8;
            int pos = atomicAdd(&cur[b], 1);
            ltgt[pos] = t_[k]; lsrc[pos] = s_[k];
        }
    }
    __syncthreads();

    for (int j = tid; j < cnt; j += 256) {
        int tv = ltgt[j];
        int b = tv >> 8;
        int dst = gstart[b] + (j - lofs[b]);
        pairs[(size_t)b * CAP + dst] = make_uint2((uint)tv, (uint)lsrc[j]);
    }
}

// pass 2: one block per bucket — fine sort by node, emit sorted src + per-node beg/cnt
__global__ __launch_bounds__(256) void k_part2(const int* __restrict__ bcur, const uint2* __restrict__ pairs,
                                               int* __restrict__ fsrc, int* __restrict__ nbeg,
                                               int* __restrict__ ncnt) {
    __shared__ int hist[256], cur[256];
    __shared__ int ws[4];
    __shared__ ushort lt[CAP];
    __shared__ int ls[CAP], ss_[CAP];
    int tid = threadIdx.x;
    int b = blockIdx.x;
    int cnt = __builtin_amdgcn_readfirstlane(bcur[b]);
    hist[tid] = 0;
    __syncthreads();

    const uint2* pb = pairs + (size_t)b * CAP;
    for (int j = tid; j < cnt; j += 256) {
        uint2 e = pb[j];
        int fine = e.x & 255;
        lt[j] = (ushort)fine; ls[j] = (int)e.y;
        atomicAdd(&hist[fine], 1);
    }
    __syncthreads();

    int v = hist[tid];
    int excl = excl_scan256(v, ws);
    int node = (b << 8) + tid;
    if (node < NN) { nbeg[node] = b * CAP + excl; ncnt[node] = v; }
    cur[tid] = excl;
    __syncthreads();

    for (int j = tid; j < cnt; j += 256) {
        int pos = atomicAdd(&cur[lt[j]], 1);
        ss_[pos] = ls[j];
    }
    __syncthreads();

    for (int j = tid; j < cnt; j += 256)
        fsrc[(size_t)b * CAP + j] = ss_[j];
}

// ---------------- Linear layers: bf16 MFMA ----------------

// Hbf = bf16(elu(X @ W1 + b1)).  M=50000, N=128, K=256.
__global__ __launch_bounds__(256) void k_linear1(const float* __restrict__ X, const float* __restrict__ W1,
                                                 const float* __restrict__ b1, ushort* __restrict__ Hb) {
    __shared__ short Bs[HIDF][INF_ + 8];
    for (int idx = threadIdx.x; idx < INF_ * HIDF; idx += 256) {
        int k = idx >> 7;
        int n = idx & (HIDF - 1);
        Bs[n][k] = f2bf(W1[idx]);
    }
    __syncthreads();

    int w = threadIdx.x >> 6;
    int l = threadIdx.x & 63;
    int m_l = l & 15, q = l >> 4;
    int row0 = blockIdx.x * 128 + w * 32;
    int rA0 = row0 + m_l;
    int rA1 = rA0 + 16;
    int rc0 = rA0 < NN ? rA0 : NN - 1;
    int rc1 = rA1 < NN ? rA1 : NN - 1;
    const float* pa0 = X + (size_t)rc0 * INF_ + q * 8;
    const float* pa1 = X + (size_t)rc1 * INF_ + q * 8;

    float4v acc[2][8] = {};
    #pragma unroll
    for (int kc = 0; kc < INF_ / 32; kc++) {
        int k0 = kc * 32;
        float4 u0 = *(const float4*)(pa0 + k0);
        float4 u1 = *(const float4*)(pa0 + k0 + 4);
        float4 v0 = *(const float4*)(pa1 + k0);
        float4 v1 = *(const float4*)(pa1 + k0 + 4);
        short8 a0, a1;
        a0[0] = f2bf(u0.x); a0[1] = f2bf(u0.y); a0[2] = f2bf(u0.z); a0[3] = f2bf(u0.w);
        a0[4] = f2bf(u1.x); a0[5] = f2bf(u1.y); a0[6] = f2bf(u1.z); a0[7] = f2bf(u1.w);
        a1[0] = f2bf(v0.x); a1[1] = f2bf(v0.y); a1[2] = f2bf(v0.z); a1[3] = f2bf(v0.w);
        a1[4] = f2bf(v1.x); a1[5] = f2bf(v1.y); a1[6] = f2bf(v1.z); a1[7] = f2bf(v1.w);
        const short* bp = &Bs[m_l][k0 + q * 8];
        #pragma unroll
        for (int n = 0; n < 8; n++) {
            short8 b = *(const short8*)(bp + n * 16 * (INF_ + 8));
            acc[0][n] = __builtin_amdgcn_mfma_f32_16x16x32_bf16(a0, b, acc[0][n], 0, 0, 0);
            acc[1][n] = __builtin_amdgcn_mfma_f32_16x16x32_bf16(a1, b, acc[1][n], 0, 0, 0);
        }
    }

    #pragma unroll
    for (int n = 0; n < 8; n++) {
        int col = n * 16 + m_l;
        float bias = b1[col];
        #pragma unroll
        for (int t = 0; t < 2; t++) {
            #pragma unroll
            for (int r = 0; r < 4; r++) {
                int row = row0 + t * 16 + q * 4 + r;
                if (row < NN) {
                    float v = acc[t][n][r] + bias;
                    v = v > 0.f ? v : expm1f(v);   // elu
                    Hb[(size_t)row * HIDF + col] = (ushort)f2bf(v);
                }
            }
        }
    }
}

// Obf = bf16(Haggbf @ W2 + b2).  M=50000, N=64, K=128, A already bf16.
__global__ __launch_bounds__(256) void k_linear2(const short* __restrict__ Hin, const float* __restrict__ W2,
                                                 const float* __restrict__ b2, ushort* __restrict__ Ob) {
    __shared__ short Bs[OUTF][HIDF + 8];
    for (int idx = threadIdx.x; idx < HIDF * OUTF; idx += 256) {
        int k = idx >> 6;
        int n = idx & (OUTF - 1);
        Bs[n][k] = f2bf(W2[idx]);
    }
    __syncthreads();

    int w = threadIdx.x >> 6;
    int l = threadIdx.x & 63;
    int m_l = l & 15, q = l >> 4;
    int row0 = blockIdx.x * 128 + w * 32;
    int rA0 = row0 + m_l;
    int rA1 = rA0 + 16;
    int rc0 = rA0 < NN ? rA0 : NN - 1;
    int rc1 = rA1 < NN ? rA1 : NN - 1;
    const short* pa0 = Hin + (size_t)rc0 * HIDF + q * 8;
    const short* pa1 = Hin + (size_t)rc1 * HIDF + q * 8;

    float4v acc[2][4] = {};
    #pragma unroll
    for (int kc = 0; kc < HIDF / 32; kc++) {
        int k0 = kc * 32;
        short8 a0 = *(const short8*)(pa0 + k0);
        short8 a1 = *(const short8*)(pa1 + k0);
        const short* bp = &Bs[m_l][k0 + q * 8];
        #pragma unroll
        for (int n = 0; n < 4; n++) {
            short8 b = *(const short8*)(bp + n * 16 * (HIDF + 8));
            acc[0][n] = __builtin_amdgcn_mfma_f32_16x16x32_bf16(a0, b, acc[0][n], 0, 0, 0);
            acc[1][n] = __builtin_amdgcn_mfma_f32_16x16x32_bf16(a1, b, acc[1][n], 0, 0, 0);
        }
    }

    #pragma unroll
    for (int n = 0; n < 4; n++) {
        int col = n * 16 + m_l;
        float bias = b2[col];
        #pragma unroll
        for (int t = 0; t < 2; t++) {
            #pragma unroll
            for (int r = 0; r < 4; r++) {
                int row = row0 + t * 16 + q * 4 + r;
                if (row < NN)
                    Ob[(size_t)row * OUTF + col] = (ushort)f2bf(acc[t][n][r] + bias);
            }
        }
    }
}

// ---------------- per-node attention scalars (bf16 inputs) ----------------

__global__ __launch_bounds__(256) void k_s1(const uint* __restrict__ Hb4, const float* __restrict__ a1w,
                                            float* __restrict__ s1s, float* __restrict__ s1t) {
    int wid  = (blockIdx.x * 256 + threadIdx.x) >> 6;
    int lane = threadIdx.x & 63;
    if (wid >= NN) return;
    uint h = Hb4[(size_t)wid * 64 + lane];          // feats 2*lane, 2*lane+1
    float h0 = bflo(h), h1 = bfhi(h);
    float2 as = ((const float2*)a1w)[lane];
    float2 at = ((const float2*)(a1w + HIDF))[lane];
    float vs = h0 * as.x + h1 * as.y;
    float vt = h0 * at.x + h1 * at.y;
    #pragma unroll
    for (int o = 32; o > 0; o >>= 1) { vs += __shfl_xor(vs, o); vt += __shfl_xor(vt, o); }
    if (lane == 0) { s1s[wid] = vs; s1t[wid] = vt; }
}

// half-wave per node (O row = 32 uints)
__global__ __launch_bounds__(256) void k_s2(const uint* __restrict__ Ob4, const float* __restrict__ a2w,
                                            float* __restrict__ s2s, float* __restrict__ s2t) {
    int wid = (blockIdx.x * 256 + threadIdx.x) >> 5;
    int li  = threadIdx.x & 31;
    if (wid >= NN) return;
    uint o = Ob4[(size_t)wid * 32 + li];
    float v0 = bflo(o), v1 = bfhi(o);
    float2 as = ((const float2*)a2w)[li];
    float2 at = ((const float2*)(a2w + OUTF))[li];
    float vs = v0 * as.x + v1 * as.y;
    float vt = v0 * at.x + v1 * at.y;
    #pragma unroll
    for (int o2 = 16; o2 > 0; o2 >>= 1) { vs += __shfl_xor(vs, o2); vt += __shfl_xor(vt, o2); }
    if (li == 0) { s2s[wid] = vs; s2t[wid] = vt; }
}

// ---------------- fused softmax + gather aggregation, one wave per node ----------------

// layer 1: gathers bf16 H rows (64 uints), writes bf16 Hagg
__global__ __launch_bounds__(256) void k_agg1f(const uint* __restrict__ Hb4, const int* __restrict__ nbeg,
                                               const int* __restrict__ ncnt, const int* __restrict__ fsrc,
                                               const float* __restrict__ ss, const float* __restrict__ st_,
                                               const float* __restrict__ ab, uint* __restrict__ Hagg4) {
    int wid  = (blockIdx.x * 256 + threadIdx.x) >> 6;
    int lane = threadIdx.x & 63;
    if (wid >= NN) return;
    int beg = __builtin_amdgcn_readfirstlane(nbeg[wid]);
    int deg = __builtin_amdgcn_readfirstlane(ncnt[wid]);
    int end = beg + deg;
    float bias = ab[0] + st_[wid];
    float ax = 0.f, ay = 0.f, bx = 0.f, by = 0.f;

    if (deg > 0 && deg <= 64) {
        // ---- fast path: one edge per lane ----
        int my_s = 0; float a = -INFINITY;
        if (lane < deg) {
            my_s = fsrc[beg + lane];
            float t = ss[my_s] + bias;
            a = t >= 0.f ? t : 0.2f * t;
        }
        float m = a;
        #pragma unroll
        for (int o = 32; o > 0; o >>= 1) m = fmaxf(m, __shfl_xor(m, o));
        float e = (lane < deg) ? __expf(a - m) : 0.f;
        float sum = e;
        #pragma unroll
        for (int o = 32; o > 0; o >>= 1) sum += __shfl_xor(sum, o);
        float p = e * (1.f / (sum + 1e-16f));
        for (int j = 0; j < deg; j += 4) {
            int s0 = __shfl(my_s, j),     s1 = __shfl(my_s, j + 1);
            int s2 = __shfl(my_s, j + 2), s3 = __shfl(my_s, j + 3);
            float w0 = __shfl(p, j),     w1 = __shfl(p, j + 1);
            float w2 = __shfl(p, j + 2), w3 = __shfl(p, j + 3);
            uint x0 = Hb4[(size_t)s0 * 64 + lane];
            uint x1 = Hb4[(size_t)s1 * 64 + lane];
            uint x2 = Hb4[(size_t)s2 * 64 + lane];
            uint x3 = Hb4[(size_t)s3 * 64 + lane];
            ax += w0 * bflo(x0); ay += w0 * bfhi(x0);
            bx += w1 * bflo(x1); by += w1 * bfhi(x1);
            ax += w2 * bflo(x2); ay += w2 * bfhi(x2);
            bx += w3 * bflo(x3); by += w3 * bfhi(x3);
        }
    } else if (deg > 64) {
        // ---- rare slow path ----
        float m = -INFINITY;
        for (int i = beg + lane; i < end; i += 64) {
            float t = ss[fsrc[i]] + bias;
            t = t >= 0.f ? t : 0.2f * t;
            m = fmaxf(m, t);
        }
        #pragma unroll
        for (int o = 32; o > 0; o >>= 1) m = fmaxf(m, __shfl_xor(m, o));
        float sum = 0.f;
        for (int i = beg + lane; i < end; i += 64) {
            float t = ss[fsrc[i]] + bias;
            t = t >= 0.f ? t : 0.2f * t;
            sum += __expf(t - m);
        }
        #pragma unroll
        for (int o = 32; o > 0; o >>= 1) sum += __shfl_xor(sum, o);
        float inv = 1.f / (sum + 1e-16f);
        for (int c = beg; c < end; c += 64) {
            int cnt = min(64, end - c);
            int my_s = 0; float p = 0.f;
            if (lane < cnt) {
                my_s = fsrc[c + lane];
                float t = ss[my_s] + bias;
                t = t >= 0.f ? t : 0.2f * t;
                p = __expf(t - m) * inv;
            }
            for (int j = 0; j < cnt; j += 4) {
                int s0 = __shfl(my_s, j),     s1 = __shfl(my_s, j + 1);
                int s2 = __shfl(my_s, j + 2), s3 = __shfl(my_s, j + 3);
                float w0 = __shfl(p, j),     w1 = __shfl(p, j + 1);
                float w2 = __shfl(p, j + 2), w3 = __shfl(p, j + 3);
                uint x0 = Hb4[(size_t)s0 * 64 + lane];
                uint x1 = Hb4[(size_t)s1 * 64 + lane];
                uint x2 = Hb4[(size_t)s2 * 64 + lane];
                uint x3 = Hb4[(size_t)s3 * 64 + lane];
                ax += w0 * bflo(x0); ay += w0 * bfhi(x0);
                bx += w1 * bflo(x1); by += w1 * bfhi(x1);
                ax += w2 * bflo(x2); ay += w2 * bfhi(x2);
                bx += w3 * bflo(x3); by += w3 * bfhi(x3);
            }
        }
    }
    float fx = ax + bx, fy = ay + by;
    uint outv = (uint)(ushort)f2bf(fx) | ((uint)(ushort)f2bf(fy) << 16);
    Hagg4[(size_t)wid * 64 + lane] = outv;
}

// layer 2: gathers bf16 O rows (32 uints; half-wave per edge), fused log_softmax
__global__ __launch_bounds__(256) void k_agg2f(const uint* __restrict__ Ob4, const int* __restrict__ nbeg,
                                               const int* __restrict__ ncnt, const int* __restrict__ fsrc,
                                               const float* __restrict__ ss, const float* __restrict__ st_,
                                               const float* __restrict__ ab, float* __restrict__ out) {
    int wid  = (blockIdx.x * 256 + threadIdx.x) >> 6;
    int lane = threadIdx.x & 63;
    if (wid >= NN) return;
    int half = lane >> 5, li = lane & 31;
    int beg = __builtin_amdgcn_readfirstlane(nbeg[wid]);
    int deg = __builtin_amdgcn_readfirstlane(ncnt[wid]);
    int end = beg + deg;
    float bias = ab[0] + st_[wid];
    float a0 = 0.f, a1 = 0.f;

    if (deg > 0 && deg <= 64) {
        int my_s = 0; float a = -INFINITY;
        if (lane < deg) {
            my_s = fsrc[beg + lane];
            float t = ss[my_s] + bias;
            a = t >= 0.f ? t : 0.2f * t;
        }
        float m = a;
        #pragma unroll
        for (int o = 32; o > 0; o >>= 1) m = fmaxf(m, __shfl_xor(m, o));
        float e = (lane < deg) ? __expf(a - m) : 0.f;
        float sum = e;
        #pragma unroll
        for (int o = 32; o > 0; o >>= 1) sum += __shfl_xor(sum, o);
        float p = e * (1.f / (sum + 1e-16f));
        for (int j = 0; j < deg; j += 4) {
            int e0 = j + half, e1 = j + 2 + half;
            int s0 = __shfl(my_s, e0), s1 = __shfl(my_s, e1);
            float w0 = __shfl(p, e0), w1 = __shfl(p, e1);
            uint x0 = Ob4[(size_t)s0 * 32 + li];
            uint x1 = Ob4[(size_t)s1 * 32 + li];
            a0 += w0 * bflo(x0); a1 += w0 * bfhi(x0);
            a0 += w1 * bflo(x1); a1 += w1 * bfhi(x1);
        }
    } else if (deg > 64) {
        float m = -INFINITY;
        for (int i = beg + lane; i < end; i += 64) {
            float t = ss[fsrc[i]] + bias;
            t = t >= 0.f ? t : 0.2f * t;
            m = fmaxf(m, t);
        }
        #pragma unroll
        for (int o = 32; o > 0; o >>= 1) m = fmaxf(m, __shfl_xor(m, o));
        float sum = 0.f;
        for (int i = beg + lane; i < end; i += 64) {
            float t = ss[fsrc[i]] + bias;
            t = t >= 0.f ? t : 0.2f * t;
            sum += __expf(t - m);
        }
        #pragma unroll
        for (int o = 32; o > 0; o >>= 1) sum += __shfl_xor(sum, o);
        float inv = 1.f / (sum + 1e-16f);
        for (int c = beg; c < end; c += 64) {
            int cnt = min(64, end - c);
            int my_s = 0; float p = 0.f;
            if (lane < cnt) {
                my_s = fsrc[c + lane];
                float t = ss[my_s] + bias;
                t = t >= 0.f ? t : 0.2f * t;
                p = __expf(t - m) * inv;
            }
            for (int j = 0; j < cnt; j += 4) {
                int e0 = j + half, e1 = j + 2 + half;
                int s0 = __shfl(my_s, e0), s1 = __shfl(my_s, e1);
                float w0 = __shfl(p, e0), w1 = __shfl(p, e1);
                uint x0 = Ob4[(size_t)s0 * 32 + li];
                uint x1 = Ob4[(size_t)s1 * 32 + li];
                a0 += w0 * bflo(x0); a1 += w0 * bfhi(x0);
                a0 += w1 * bflo(x1); a1 += w1 * bfhi(x1);
            }
        }
    }
    // combine the two edge-halves
    a0 += __shfl_xor(a0, 32);
    a1 += __shfl_xor(a1, 32);
    // log_softmax over 64 feats (2 per lane across each 32-lane half)
    float mx = fmaxf(a0, a1);
    #pragma unroll
    for (int o = 16; o > 0; o >>= 1) mx = fmaxf(mx, __shfl_xor(mx, o));
    float es = __expf(a0 - mx) + __expf(a1 - mx);
    #pragma unroll
    for (int o = 16; o > 0; o >>= 1) es += __shfl_xor(es, o);
    float lg = __logf(es);
    if (half == 0) {
        float2 r; r.x = a0 - mx - lg; r.y = a1 - mx - lg;
        ((float2*)out)[(size_t)wid * 32 + li] = r;
    }
}

// ---------------- launcher ----------------

extern "C" void kernel_launch(void* const* d_in, const int* in_sizes, int n_in,
                              void* d_out, int out_size, void* d_ws, size_t ws_size,
                              hipStream_t stream) {
    const float* X   = (const float*)d_in[0];
    const int*   ei  = (const int*)d_in[1];
    const float* W1  = (const float*)d_in[2];
    const float* b1  = (const float*)d_in[3];
    const float* a1w = (const float*)d_in[4];
    const float* a1b = (const float*)d_in[5];
    const float* W2  = (const float*)d_in[6];
    const float* b2  = (const float*)d_in[7];
    const float* a2w = (const float*)d_in[8];
    const float* a2b = (const float*)d_in[9];
    const int* src = ei;           // edge_index[0]
    const int* tgt = ei + NE;      // edge_index[1]

    char* p = (char*)d_ws;
    size_t off = 0;
    auto alloc = [&](size_t bytes) -> char* {
        char* r = p + off;
        off = (off + bytes + 255) & ~(size_t)255;
        return r;
    };
    ushort* Hb    = (ushort*)alloc((size_t)NN * HIDF * 2);
    ushort* Hagg  = (ushort*)alloc((size_t)NN * HIDF * 2);
    ushort* Ob    = (ushort*)alloc((size_t)NN * OUTF * 2);
    float* s1s    = (float*)alloc((size_t)NN * 4);
    float* s1t    = (float*)alloc((size_t)NN * 4);
    float* s2s    = (float*)alloc((size_t)NN * 4);
    float* s2t    = (float*)alloc((size_t)NN * 4);
    int*   bcur   = (int*)alloc((size_t)NBUCK * 4);
    uint2* pairs  = (uint2*)alloc((size_t)NBUCK * CAP * 8);
    int*   fsrc   = (int*)alloc((size_t)NBUCK * CAP * 4);
    int*   nbeg   = (int*)alloc((size_t)NN * 4);
    int*   ncnt   = (int*)alloc((size_t)NN * 4);

    hipMemsetAsync(bcur, 0, (size_t)NBUCK * 4, stream);
    k_part1  <<<(NE + CHUNK - 1) / CHUNK, 256, 0, stream>>>(src, tgt, bcur, pairs);
    k_part2  <<<NBUCK, 256, 0, stream>>>(bcur, pairs, fsrc, nbeg, ncnt);

    k_linear1<<<(NN + 127) / 128, 256, 0, stream>>>(X, W1, b1, Hb);
    k_s1     <<<NN / 4, 256, 0, stream>>>((const uint*)Hb, a1w, s1s, s1t);
    k_agg1f  <<<NN / 4, 256, 0, stream>>>((const uint*)Hb, nbeg, ncnt, fsrc, s1s, s1t, a1b, (uint*)Hagg);

    k_linear2<<<(NN + 127) / 128, 256, 0, stream>>>((const short*)Hagg, W2, b2, Ob);
    k_s2     <<<NN / 8, 256, 0, stream>>>((const uint*)Ob, a2w, s2s, s2t);
    k_agg2f  <<<NN / 4, 256, 0, stream>>>((const uint*)Ob, nbeg, ncnt, fsrc, s2s, s2t, a2b, (float*)d_out);
}